// Round 2
// baseline (1327.914 us; speedup 1.0000x reference)
//
#include <hip/hip_runtime.h>
#include <math.h>

#define B_ 32
#define LK 4096
#define C_ 512
#define H_ 8
#define DH 64
#define U_ 22
#define HU 176
#define HUP 192
#define SK 45
#define NTOP 20
#define DFF 2048
#define EPSF 1e-5f

typedef unsigned short u16;
typedef __attribute__((ext_vector_type(8))) short short8;
typedef __attribute__((ext_vector_type(4))) short short4v;
typedef __attribute__((ext_vector_type(8))) unsigned short ushort8;
typedef __attribute__((ext_vector_type(4))) unsigned short ushort4v;
typedef __attribute__((ext_vector_type(4))) float f32x4;

__device__ __forceinline__ u16 f2b(float f){
  union{float f;unsigned u;} v; v.f=f;
  unsigned r=(v.u + 0x7FFFu + ((v.u>>16)&1u))>>16;
  return (u16)r;
}
__device__ __forceinline__ float b2f(u16 h){
  union{unsigned u;float f;} v; v.u=((unsigned)h)<<16; return v.f;
}
// Build an 8-elem bf16 fragment: elems 0-3 at p[0..3], elems 4-7 at p[16..19].
// Same pattern for A and B => result invariant to HW's internal k-permutation.
__device__ __forceinline__ short8 ldfrag(const u16* p){
  short4v lo=*(const short4v*)p;
  short4v hi=*(const short4v*)(p+16);
  short8 r;
  r[0]=lo[0];r[1]=lo[1];r[2]=lo[2];r[3]=lo[3];
  r[4]=hi[0];r[5]=hi[1];r[6]=hi[2];r[7]=hi[3];
  return r;
}
__device__ __forceinline__ float blocksum(float v, float* red){
  for(int off=32;off;off>>=1) v+=__shfl_xor(v,off);
  int w=threadIdx.x>>6, lane=threadIdx.x&63;
  if(lane==0) red[w]=v;
  __syncthreads();
  float r=red[0]+red[1]+red[2]+red[3];
  __syncthreads();
  return r;
}

// ---------------- K1: positional encoding -> q = pe@Wq + bq  (22 x 512) -----
__global__ void k_prep_q(const float* __restrict__ Wq, const float* __restrict__ bq,
                         float* __restrict__ q){
  __shared__ float pe[C_];
  int u=blockIdx.x, t=threadIdx.x;
  float lg = logf(10000.0f)/(float)C_;
  for(int c=t;c<C_;c+=256){
    int i=c>>1;
    float arg=(float)u*expf(-(float)(2*i)*lg);
    pe[c]=(c&1)?cosf(arg):sinf(arg);
  }
  __syncthreads();
  for(int col=t;col<C_;col+=256){
    float acc=0.f;
    for(int c=0;c<C_;c++) acc+=pe[c]*Wq[c*C_+col];
    q[u*C_+col]=acc+bq[col];
  }
}

// ---------------- K2: q_effK[hu][c] = sum_d q[u][h*64+d]*Wk[c][h*64+d] ------
__global__ void k_qeff(const float* __restrict__ q, const float* __restrict__ Wk,
                       float* __restrict__ qef, u16* __restrict__ qeb){
  int hu=blockIdx.x, t=threadIdx.x;
  int h=hu/U_, u=hu-h*U_;
  __shared__ float qr[DH];
  bool valid=(hu<HU);
  if(t<DH) qr[t]=valid? q[u*C_+h*DH+t] : 0.f;
  __syncthreads();
  for(int c=t;c<C_;c+=256){
    float acc=0.f;
    if(valid){
      const float* wrow=Wk+(size_t)c*C_+h*DH;
      for(int d=0;d<DH;d++) acc+=qr[d]*wrow[d];
    }
    qef[hu*C_+c]=acc;
    qeb[hu*C_+c]=f2b(acc);
  }
}

// ---------------- K3: sampled scores -> M -> top-20 mask (fp32 exact path) --
__global__ void k_sample(const float* __restrict__ enc, const float* __restrict__ qef,
                         unsigned* __restrict__ selmask){
  int bh=blockIdx.x, t=threadIdx.x;
  int b=bh>>3, h=bh&7;
  __shared__ float es[SK][132];
  __shared__ float qe[U_][132];
  __shared__ float qk[U_][SK+3];
  __shared__ float Mv[U_];
  float acc[4]={0.f,0.f,0.f,0.f};
  for(int c0=0;c0<C_;c0+=128){
    __syncthreads();
    for(int i=t;i<SK*128;i+=256){
      int ks=i>>7, c=i&127;
      int row=(ks*LK)/SK;
      es[ks][c]=enc[((size_t)b*LK+row)*C_+c0+c];
    }
    for(int i=t;i<U_*128;i+=256){
      int u=i>>7, c=i&127;
      qe[u][c]=qef[(h*U_+u)*C_+c0+c];
    }
    __syncthreads();
    for(int dd=0;dd<4;dd++){
      int d=t+dd*256;
      if(d<U_*SK){
        int u=d/SK, ks=d-u*SK;
        float s=0.f;
        for(int c=0;c<128;c++) s+=qe[u][c]*es[ks][c];
        acc[dd]+=s;
      }
    }
  }
  for(int dd=0;dd<4;dd++){
    int d=t+dd*256;
    if(d<U_*SK){ int u=d/SK, ks=d-u*SK; qk[u][ks]=acc[dd]; }
  }
  __syncthreads();
  if(t<U_){
    float mx=-1e30f, sm=0.f;
    for(int ks=0;ks<SK;ks++){ float v=qk[t][ks]; mx=fmaxf(mx,v); sm+=v; }
    Mv[t]=mx-sm/(float)SK;
  }
  __syncthreads();
  if(t<64){
    bool sel=false;
    if(t<U_){
      float m=Mv[t]; int rank=0;
      for(int u2=0;u2<U_;u2++){
        float o=Mv[u2];
        if(o>m || (o==m && u2<t)) rank++;
      }
      sel=(rank<NTOP);
    }
    unsigned long long bal=__ballot(sel);
    if(t==0) selmask[bh]=(unsigned)(bal&0x3FFFFFull);
  }
}

// ---------------- K4: enc fp32 -> enc_bf16 [l][c]  AND  encT_bf16 [c][l] ----
__global__ void k_convert(const float* __restrict__ enc, u16* __restrict__ encb,
                          u16* __restrict__ encT){
  int ct=blockIdx.x, lt=blockIdx.y, b=blockIdx.z, t=threadIdx.x;
  __shared__ __align__(16) u16 tile[64][72];
  int l0=lt*64, c0=ct*64;
  for(int p=0;p<4;p++){
    int lr=p*16+(t>>4);
    int cc=(t&15)*4;
    float4 v=*(const float4*)&enc[((size_t)b*LK+l0+lr)*C_+c0+cc];
    u16 h0=f2b(v.x),h1=f2b(v.y),h2=f2b(v.z),h3=f2b(v.w);
    ushort4v o; o[0]=h0;o[1]=h1;o[2]=h2;o[3]=h3;
    *(ushort4v*)&encb[((size_t)b*LK+l0+lr)*C_+c0+cc]=o;
    tile[cc+0][lr]=h0; tile[cc+1][lr]=h1; tile[cc+2][lr]=h2; tile[cc+3][lr]=h3;
  }
  __syncthreads();
  for(int p=0;p<2;p++){
    int cr=p*32+(t>>3), loff=(t&7)*8;
    ushort8 w=*(const ushort8*)&tile[cr][loff];
    *(ushort8*)&encT[((size_t)b*C_+c0+cr)*LK+l0+loff]=w;
  }
}

// ---------------- K5: column sums of enc (from encT rows) -------------------
__global__ void k_colsum(const u16* __restrict__ encT, float* __restrict__ encsum){
  int b=blockIdx.x;
  int w=threadIdx.x>>6, lane=threadIdx.x&63;
  int c=blockIdx.y*4+w;
  const u16* row=encT+((size_t)b*C_+c)*LK;
  float s=0.f;
  for(int i=0;i<8;i++){
    ushort8 v=*(const ushort8*)&row[(i*64+lane)*8];
    for(int j=0;j<8;j++) s+=b2f(v[j]);
  }
  for(int off=32;off;off>>=1) s+=__shfl_down(s,off);
  if(lane==0) encsum[b*C_+c]=s;
}

// ---------------- K6: scores S[b][hu][l] = q_effK @ enc^T  (bf16 MFMA) ------
// mt fastest-varying: the 6 blocks sharing one encb tile dispatch consecutively.
__global__ __launch_bounds__(256) void k_scores(const u16* __restrict__ encb,
                                                const u16* __restrict__ qeb,
                                                u16* __restrict__ S){
  int mt=blockIdx.x, nt=blockIdx.y, b=blockIdx.z, t=threadIdx.x;
  __shared__ __align__(16) u16 qe[32][520];
  __shared__ __align__(16) u16 et[256][40];
  int hu0=mt*32, l0=nt*256;
  for(int i=t;i<32*64;i+=256){
    int r=i>>6, cc=(i&63)*8;
    *(ushort8*)&qe[r][cc]=*(const ushort8*)&qeb[(hu0+r)*C_+cc];
  }
  int w=t>>6, lane=t&63;
  int arow=lane&15, kgrp=(lane>>4)*4;
  f32x4 acc[2][4];
  #pragma unroll
  for(int i=0;i<2;i++)
    #pragma unroll
    for(int j=0;j<4;j++) acc[i][j]=(f32x4){0.f,0.f,0.f,0.f};
  for(int kc=0;kc<C_;kc+=32){
    __syncthreads();
    for(int i=t;i<1024;i+=256){
      int l=i>>2, off=(i&3)*8;
      *(ushort8*)&et[l][off]=*(const ushort8*)&encb[((size_t)b*LK+l0+l)*C_+kc+off];
    }
    __syncthreads();
    short8 af0=ldfrag(&qe[arow][kc+kgrp]);
    short8 af1=ldfrag(&qe[16+arow][kc+kgrp]);
    #pragma unroll
    for(int ns=0;ns<4;ns++){
      short8 bf=ldfrag(&et[w*64+ns*16+arow][kgrp]);
      acc[0][ns]=__builtin_amdgcn_mfma_f32_16x16x32_bf16(af0,bf,acc[0][ns],0,0,0);
      acc[1][ns]=__builtin_amdgcn_mfma_f32_16x16x32_bf16(af1,bf,acc[1][ns],0,0,0);
    }
  }
  int dcol=lane&15, drow=(lane>>4)*4;
  #pragma unroll
  for(int ms=0;ms<2;ms++)
    #pragma unroll
    for(int ns=0;ns<4;ns++){
      size_t base=((size_t)b*HUP+hu0+ms*16+drow)*LK + l0 + w*64 + ns*16 + dcol;
      #pragma unroll
      for(int r=0;r<4;r++)
        S[base+(size_t)r*LK]=f2b(acc[ms][ns][r]);
    }
}

// ---------------- K7: row softmax over l (scale 1/8), in place --------------
__global__ void k_softmax(u16* __restrict__ S){
  int hu=blockIdx.x, b=blockIdx.y, t=threadIdx.x;
  u16* row=S+((size_t)b*HUP+hu)*LK;
  __shared__ float red[8];
  __shared__ float red2[8];
  float v[16];
  ushort8 r0=*(const ushort8*)&row[t*16];
  ushort8 r1=*(const ushort8*)&row[t*16+8];
  #pragma unroll
  for(int j=0;j<8;j++){ v[j]=b2f(r0[j]); v[8+j]=b2f(r1[j]); }
  float mx=-1e30f;
  #pragma unroll
  for(int j=0;j<16;j++) mx=fmaxf(mx,v[j]);
  for(int off=32;off;off>>=1) mx=fmaxf(mx,__shfl_xor(mx,off));
  int w=t>>6, lane=t&63;
  if(lane==0) red[w]=mx;
  __syncthreads();
  mx=fmaxf(fmaxf(red[0],red[1]),fmaxf(red[2],red[3]));
  const float scale=0.125f;
  float sm=0.f;
  #pragma unroll
  for(int j=0;j<16;j++){ v[j]=__expf((v[j]-mx)*scale); sm+=v[j]; }
  for(int off=32;off;off>>=1) sm+=__shfl_xor(sm,off);
  if(lane==0) red2[w]=sm;
  __syncthreads();
  sm=red2[0]+red2[1]+red2[2]+red2[3];
  float inv=1.f/sm;
  ushort8 o0,o1;
  #pragma unroll
  for(int j=0;j<8;j++){ o0[j]=f2b(v[j]*inv); o1[j]=f2b(v[8+j]*inv); }
  *(ushort8*)&row[t*16]=o0;
  *(ushort8*)&row[t*16+8]=o1;
}

// ---------------- K8: ctxA[b][hu][c] = attn @ enc  (bf16 MFMA, K=4096) ------
// mt fastest-varying: the 4 blocks sharing one encT c-tile dispatch consecutively.
__global__ __launch_bounds__(256) void k_pv(const u16* __restrict__ S,
                                            const u16* __restrict__ encT,
                                            float* __restrict__ ctxA){
  int mt=blockIdx.x, nt=blockIdx.y, b=blockIdx.z, t=threadIdx.x;
  __shared__ __align__(16) u16 pa[48][72];
  __shared__ __align__(16) u16 et[128][72];
  int hu0=mt*48, c0=nt*128;
  int w=t>>6, lane=t&63;
  int arow=lane&15, kgrp=(lane>>4)*4;
  f32x4 acc[3][2];
  #pragma unroll
  for(int i=0;i<3;i++)
    #pragma unroll
    for(int j=0;j<2;j++) acc[i][j]=(f32x4){0.f,0.f,0.f,0.f};
  for(int l0=0;l0<LK;l0+=64){
    __syncthreads();
    for(int i=t;i<384;i+=256){
      int r=i>>3, off=(i&7)*8;
      *(ushort8*)&pa[r][off]=*(const ushort8*)&S[((size_t)b*HUP+hu0+r)*LK+l0+off];
    }
    for(int i=t;i<1024;i+=256){
      int r=i>>3, off=(i&7)*8;
      *(ushort8*)&et[r][off]=*(const ushort8*)&encT[((size_t)b*C_+c0+r)*LK+l0+off];
    }
    __syncthreads();
    #pragma unroll
    for(int ks=0;ks<2;ks++){
      short8 af0=ldfrag(&pa[arow][ks*32+kgrp]);
      short8 af1=ldfrag(&pa[16+arow][ks*32+kgrp]);
      short8 af2=ldfrag(&pa[32+arow][ks*32+kgrp]);
      #pragma unroll
      for(int ns=0;ns<2;ns++){
        short8 bf=ldfrag(&et[w*32+ns*16+arow][ks*32+kgrp]);
        acc[0][ns]=__builtin_amdgcn_mfma_f32_16x16x32_bf16(af0,bf,acc[0][ns],0,0,0);
        acc[1][ns]=__builtin_amdgcn_mfma_f32_16x16x32_bf16(af1,bf,acc[1][ns],0,0,0);
        acc[2][ns]=__builtin_amdgcn_mfma_f32_16x16x32_bf16(af2,bf,acc[2][ns],0,0,0);
      }
    }
  }
  int dcol=lane&15, drow=(lane>>4)*4;
  #pragma unroll
  for(int m=0;m<3;m++)
    #pragma unroll
    for(int ns=0;ns<2;ns++)
      #pragma unroll
      for(int r=0;r<4;r++){
        int hu=hu0+m*16+drow+r, c=c0+w*32+ns*16+dcol;
        ctxA[((size_t)b*HUP+hu)*C_+c]=acc[m][ns][r];
      }
}

// ---------------- K9: ctx[b][u][hd] = (sel? ctxA : enc_mean) @ Wv + bv ------
__global__ void k_ctxproj(const float* __restrict__ ctxA, const float* __restrict__ encsum,
                          const unsigned* __restrict__ selmask, const float* __restrict__ Wv,
                          const float* __restrict__ bv, float* __restrict__ ctx){
  int u=blockIdx.x, b=blockIdx.y, t=threadIdx.x;
  __shared__ float R[H_][C_];
  for(int h=0;h<H_;h++){
    bool sel=(selmask[b*H_+h]>>u)&1u;
    const float* src=sel? &ctxA[((size_t)b*HUP+h*U_+u)*C_] : &encsum[b*C_];
    float sc=sel? 1.f : (1.f/(float)LK);
    for(int c=t;c<C_;c+=256) R[h][c]=src[c]*sc;
  }
  __syncthreads();
  for(int hd=t;hd<C_;hd+=256){
    int h=hd>>6;
    float a=0.f;
    for(int c=0;c<C_;c++) a+=R[h][c]*Wv[(size_t)c*C_+hd];
    ctx[((size_t)(b*U_+u))*C_+hd]=a+bv[hd];
  }
}

// ---------------- K10: attn_out = ctx@Wo+bo ; x = LN(2*attn_out) ------------
__global__ void k_wo_ln1(const float* __restrict__ ctx, const float* __restrict__ Wo,
                         const float* __restrict__ bo, const float* __restrict__ g1,
                         const float* __restrict__ be1, float* __restrict__ x){
  int u=blockIdx.x, b=blockIdx.y, t=threadIdx.x;
  __shared__ float row[C_];
  __shared__ float red[8];
  size_t r0=(size_t)(b*U_+u)*C_;
  for(int c=t;c<C_;c+=256) row[c]=ctx[r0+c];
  __syncthreads();
  float a0=0.f,a1=0.f;
  for(int c=0;c<C_;c++){
    float rv=row[c];
    a0+=rv*Wo[(size_t)c*C_+t];
    a1+=rv*Wo[(size_t)c*C_+t+256];
  }
  a0=2.f*(a0+bo[t]); a1=2.f*(a1+bo[t+256]);
  float mu=blocksum(a0+a1,red)*(1.f/(float)C_);
  float d0=a0-mu, d1=a1-mu;
  float var=blocksum(d0*d0+d1*d1,red)*(1.f/(float)C_);
  float rs=rsqrtf(var+EPSF);
  x[r0+t]=d0*rs*g1[t]+be1[t];
  x[r0+t+256]=d1*rs*g1[t+256]+be1[t+256];
}

// ---------------- K11: ff1 = relu(x @ W1^T + b1)  (704x2048, K=512) ---------
__global__ __launch_bounds__(256) void k_ff1(const float* __restrict__ A,
                                             const float* __restrict__ W,
                                             const float* __restrict__ bias,
                                             float* __restrict__ out){
  int ntile=blockIdx.x, mtile=blockIdx.y, t=threadIdx.x;
  __shared__ float Wt[256][33];
  __shared__ float At[16][33];
  float acc[16];
  #pragma unroll
  for(int i=0;i<16;i++) acc[i]=0.f;
  int n0=ntile*256, m0=mtile*16;
  for(int kc=0;kc<512;kc+=32){
    __syncthreads();
    for(int i=t;i<2048;i+=256){
      int n=i>>3, off=(i&7)*4;
      float4 v=*(const float4*)&W[(size_t)(n0+n)*512+kc+off];
      Wt[n][off]=v.x; Wt[n][off+1]=v.y; Wt[n][off+2]=v.z; Wt[n][off+3]=v.w;
    }
    for(int i=t;i<128;i+=256){
      int m=i>>3, off=(i&7)*4;
      float4 v=*(const float4*)&A[(size_t)(m0+m)*512+kc+off];
      At[m][off]=v.x; At[m][off+1]=v.y; At[m][off+2]=v.z; At[m][off+3]=v.w;
    }
    __syncthreads();
    for(int k=0;k<32;k++){
      float wv=Wt[t][k];
      #pragma unroll
      for(int m=0;m<16;m++) acc[m]+=At[m][k]*wv;
    }
  }
  float bb=bias[n0+t];
  #pragma unroll
  for(int m=0;m<16;m++){
    float v=acc[m]+bb;
    out[(size_t)(m0+m)*DFF+n0+t]=v>0.f?v:0.f;
  }
}

// ---------------- K12: ff2 partial (K split in 4) with atomicAdd ------------
__global__ __launch_bounds__(256) void k_ff2(const float* __restrict__ A,
                                             const float* __restrict__ W,
                                             float* __restrict__ out){
  int ntile=blockIdx.x, mtile=blockIdx.y, kchunk=blockIdx.z, t=threadIdx.x;
  __shared__ float Wt[256][33];
  __shared__ float At[16][33];
  float acc[16];
  #pragma unroll
  for(int i=0;i<16;i++) acc[i]=0.f;
  int n0=ntile*256, m0=mtile*16, k0=kchunk*512;
  for(int kc=0;kc<512;kc+=32){
    __syncthreads();
    for(int i=t;i<2048;i+=256){
      int n=i>>3, off=(i&7)*4;
      float4 v=*(const float4*)&W[(size_t)(n0+n)*DFF+k0+kc+off];
      Wt[n][off]=v.x; Wt[n][off+1]=v.y; Wt[n][off+2]=v.z; Wt[n][off+3]=v.w;
    }
    for(int i=t;i<128;i+=256){
      int m=i>>3, off=(i&7)*4;
      float4 v=*(const float4*)&A[(size_t)(m0+m)*DFF+k0+kc+off];
      At[m][off]=v.x; At[m][off+1]=v.y; At[m][off+2]=v.z; At[m][off+3]=v.w;
    }
    __syncthreads();
    for(int k=0;k<32;k++){
      float wv=Wt[t][k];
      #pragma unroll
      for(int m=0;m<16;m++) acc[m]+=At[m][k]*wv;
    }
  }
  #pragma unroll
  for(int m=0;m<16;m++) atomicAdd(&out[(size_t)(m0+m)*C_+n0+t],acc[m]);
}

// ---------------- K13: y = LN(x + ff2 + b2); forecasts = y@Wout + bout ------
__global__ void k_ln2(const float* __restrict__ x, const float* __restrict__ ff2,
                      const float* __restrict__ b2, const float* __restrict__ g2,
                      const float* __restrict__ be2, const float* __restrict__ Wout,
                      const float* __restrict__ bout, float* __restrict__ dout){
  int u=blockIdx.x, b=blockIdx.y, t=threadIdx.x;
  __shared__ float red[8];
  size_t r0=(size_t)(b*U_+u)*C_;
  float s0=x[r0+t]+ff2[r0+t]+b2[t];
  float s1=x[r0+t+256]+ff2[r0+t+256]+b2[t+256];
  float mu=blocksum(s0+s1,red)*(1.f/(float)C_);
  float d0=s0-mu, d1=s1-mu;
  float var=blocksum(d0*d0+d1*d1,red)*(1.f/(float)C_);
  float rs=rsqrtf(var+EPSF);
  float y0=d0*rs*g2[t]+be2[t];
  float y1=d1*rs*g2[t+256]+be2[t+256];
  float* Y=dout+B_*U_;
  Y[r0+t]=y0;
  Y[r0+t+256]=y1;
  float f=blocksum(y0*Wout[t]+y1*Wout[t+256],red);
  if(t==0) dout[b*U_+u]=f+bout[0];
}

extern "C" void kernel_launch(void* const* d_in, const int* in_sizes, int n_in,
                              void* d_out, int out_size, void* d_ws, size_t ws_size,
                              hipStream_t stream){
  (void)in_sizes;(void)n_in;(void)out_size;(void)ws_size;
  const float* enc =(const float*)d_in[0];
  const float* Wq  =(const float*)d_in[1];
  const float* bq  =(const float*)d_in[2];
  const float* Wk  =(const float*)d_in[3];
  // d_in[4] = bk: provably cancels (row-constant shift, softmax/max-mean invariant)
  const float* Wv  =(const float*)d_in[5];
  const float* bv  =(const float*)d_in[6];
  const float* Wo  =(const float*)d_in[7];
  const float* bo  =(const float*)d_in[8];
  const float* W1  =(const float*)d_in[9];
  const float* b1  =(const float*)d_in[10];
  const float* W2  =(const float*)d_in[11];
  const float* b2  =(const float*)d_in[12];
  const float* g1  =(const float*)d_in[13];
  const float* be1 =(const float*)d_in[14];
  const float* g2  =(const float*)d_in[15];
  const float* be2 =(const float*)d_in[16];
  const float* Wout=(const float*)d_in[17];
  const float* bout=(const float*)d_in[18];

  char* ws=(char*)d_ws;
  float*    q      =(float*)   (ws+0);           //  45,056 B
  float*    qef    =(float*)   (ws+45056);       // 393,216 B (192 rows, pad zeroed)
  u16*      qeb    =(u16*)     (ws+438272);      // 196,608 B
  unsigned* selmask=(unsigned*)(ws+634880);      //   1,024 B
  float*    encsum =(float*)   (ws+635904);      //  65,536 B
  u16*      encb   =(u16*)     (ws+701440);      // 134,217,728 B (dead after k_scores)
  u16*      encT   =(u16*)     (ws+134919168);   // 134,217,728 B
  u16*      S      =(u16*)     (ws+269136896);   //  50,331,648 B  (high water ~319.5 MB)
  // overlays into the dead encb region:
  float*    ctxA   =(float*)   (ws+701440);      //  12,582,912 B
  float*    ctx    =(float*)   (ws+13284352);    //   1,441,792 B
  float*    x      =(float*)   (ws+14726144);    //   1,441,792 B
  float*    ff1    =(float*)   (ws+16167936);    //   5,767,168 B
  float*    ff2    =(float*)   (ws+21935104);    //   1,441,792 B

  hipLaunchKernelGGL(k_prep_q, dim3(22),      dim3(256),0,stream, Wq,bq,q);
  hipLaunchKernelGGL(k_qeff,   dim3(192),     dim3(256),0,stream, q,Wk,qef,qeb);
  hipLaunchKernelGGL(k_sample, dim3(256),     dim3(256),0,stream, enc,qef,selmask);
  hipLaunchKernelGGL(k_convert,dim3(8,64,32), dim3(256),0,stream, enc,encb,encT);
  hipLaunchKernelGGL(k_colsum, dim3(32,128),  dim3(256),0,stream, encT,encsum);
  hipLaunchKernelGGL(k_scores, dim3(6,16,32), dim3(256),0,stream, encb,qeb,S);
  hipLaunchKernelGGL(k_softmax,dim3(192,32),  dim3(256),0,stream, S);
  hipLaunchKernelGGL(k_pv,     dim3(4,4,32),  dim3(256),0,stream, S,encT,ctxA);
  hipLaunchKernelGGL(k_ctxproj,dim3(22,32),   dim3(256),0,stream, ctxA,encsum,selmask,Wv,bv,ctx);
  hipLaunchKernelGGL(k_wo_ln1, dim3(22,32),   dim3(256),0,stream, ctx,Wo,bo,g1,be1,x);
  hipLaunchKernelGGL(k_ff1,    dim3(8,44),    dim3(256),0,stream, x,W1,b1,ff1);
  hipMemsetAsync(ff2,0,1441792,stream);
  hipLaunchKernelGGL(k_ff2,    dim3(2,44,4),  dim3(256),0,stream, ff1,W2,ff2);
  hipLaunchKernelGGL(k_ln2,    dim3(22,32),   dim3(256),0,stream, x,ff2,b2,g2,be2,Wout,bout,(float*)d_out);
}

// Round 4
// 1055.391 us; speedup vs baseline: 1.2582x; 1.2582x over previous
//
#include <hip/hip_runtime.h>
#include <math.h>

#define B_ 32
#define LK 4096
#define C_ 512
#define H_ 8
#define DH 64
#define U_ 22
#define HU 176
#define HUP 192
#define SK 45
#define NTOP 20
#define DFF 2048
#define EPSF 1e-5f

typedef unsigned short u16;
typedef __attribute__((ext_vector_type(8))) short short8;
typedef __attribute__((ext_vector_type(4))) short short4v;
typedef __attribute__((ext_vector_type(8))) unsigned short ushort8;
typedef __attribute__((ext_vector_type(4))) unsigned short ushort4v;
typedef __attribute__((ext_vector_type(4))) float f32x4;

__device__ __forceinline__ u16 f2b(float f){
  union{float f;unsigned u;} v; v.f=f;
  unsigned r=(v.u + 0x7FFFu + ((v.u>>16)&1u))>>16;
  return (u16)r;
}
__device__ __forceinline__ float b2f(u16 h){
  union{unsigned u;float f;} v; v.u=((unsigned)h)<<16; return v.f;
}
// Build an 8-elem bf16 fragment: elems 0-3 at p[0..3], elems 4-7 at p[16..19].
// Same pattern for A and B => result invariant to HW's internal k-permutation.
__device__ __forceinline__ short8 ldfrag(const u16* p){
  short4v lo=*(const short4v*)p;
  short4v hi=*(const short4v*)(p+16);
  short8 r;
  r[0]=lo[0];r[1]=lo[1];r[2]=lo[2];r[3]=lo[3];
  r[4]=hi[0];r[5]=hi[1];r[6]=hi[2];r[7]=hi[3];
  return r;
}
__device__ __forceinline__ float blocksum(float v, float* red){
  for(int off=32;off;off>>=1) v+=__shfl_xor(v,off);
  int w=threadIdx.x>>6, lane=threadIdx.x&63;
  if(lane==0) red[w]=v;
  __syncthreads();
  float r=red[0]+red[1]+red[2]+red[3];
  __syncthreads();
  return r;
}

// ---------------- K1: positional encoding -> q = pe@Wq + bq  (22 x 512) -----
__global__ void k_prep_q(const float* __restrict__ Wq, const float* __restrict__ bq,
                         float* __restrict__ q){
  __shared__ float pe[C_];
  int u=blockIdx.x, t=threadIdx.x;
  float lg = logf(10000.0f)/(float)C_;
  for(int c=t;c<C_;c+=256){
    int i=c>>1;
    float arg=(float)u*expf(-(float)(2*i)*lg);
    pe[c]=(c&1)?cosf(arg):sinf(arg);
  }
  __syncthreads();
  for(int col=t;col<C_;col+=256){
    float acc=0.f;
    for(int c=0;c<C_;c++) acc+=pe[c]*Wq[c*C_+col];
    q[u*C_+col]=acc+bq[col];
  }
}

// ---------------- K2: q_effK[hu][c] = sum_d q[u][h*64+d]*Wk[c][h*64+d] ------
__global__ void k_qeff(const float* __restrict__ q, const float* __restrict__ Wk,
                       float* __restrict__ qef, u16* __restrict__ qeb){
  int hu=blockIdx.x, t=threadIdx.x;
  int h=hu/U_, u=hu-h*U_;
  __shared__ float qr[DH];
  bool valid=(hu<HU);
  if(t<DH) qr[t]=valid? q[u*C_+h*DH+t] : 0.f;
  __syncthreads();
  for(int c=t;c<C_;c+=256){
    float acc=0.f;
    if(valid){
      const float* wrow=Wk+(size_t)c*C_+h*DH;
      for(int d=0;d<DH;d++) acc+=qr[d]*wrow[d];
    }
    qef[hu*C_+c]=acc;
    qeb[hu*C_+c]=f2b(acc);
  }
}

// ---------------- K3: sampled scores -> M -> top-20 mask (fp32 exact path) --
__global__ void k_sample(const float* __restrict__ enc, const float* __restrict__ qef,
                         unsigned* __restrict__ selmask){
  int bh=blockIdx.x, t=threadIdx.x;
  int b=bh>>3, h=bh&7;
  __shared__ float es[SK][132];
  __shared__ float qe[U_][132];
  __shared__ float qk[U_][SK+3];
  __shared__ float Mv[U_];
  float acc[4]={0.f,0.f,0.f,0.f};
  for(int c0=0;c0<C_;c0+=128){
    __syncthreads();
    for(int i=t;i<SK*128;i+=256){
      int ks=i>>7, c=i&127;
      int row=(ks*LK)/SK;
      es[ks][c]=enc[((size_t)b*LK+row)*C_+c0+c];
    }
    for(int i=t;i<U_*128;i+=256){
      int u=i>>7, c=i&127;
      qe[u][c]=qef[(h*U_+u)*C_+c0+c];
    }
    __syncthreads();
    for(int dd=0;dd<4;dd++){
      int d=t+dd*256;
      if(d<U_*SK){
        int u=d/SK, ks=d-u*SK;
        float s=0.f;
        for(int c=0;c<128;c++) s+=qe[u][c]*es[ks][c];
        acc[dd]+=s;
      }
    }
  }
  for(int dd=0;dd<4;dd++){
    int d=t+dd*256;
    if(d<U_*SK){ int u=d/SK, ks=d-u*SK; qk[u][ks]=acc[dd]; }
  }
  __syncthreads();
  if(t<U_){
    float mx=-1e30f, sm=0.f;
    for(int ks=0;ks<SK;ks++){ float v=qk[t][ks]; mx=fmaxf(mx,v); sm+=v; }
    Mv[t]=mx-sm/(float)SK;
  }
  __syncthreads();
  if(t<64){
    bool sel=false;
    if(t<U_){
      float m=Mv[t]; int rank=0;
      for(int u2=0;u2<U_;u2++){
        float o=Mv[u2];
        if(o>m || (o==m && u2<t)) rank++;
      }
      sel=(rank<NTOP);
    }
    unsigned long long bal=__ballot(sel);
    if(t==0) selmask[bh]=(unsigned)(bal&0x3FFFFFull);
  }
}

// ---------------- K4: enc fp32 -> enc_bf16 [l][c]  AND  encT_bf16 [c][l] ----
__global__ void k_convert(const float* __restrict__ enc, u16* __restrict__ encb,
                          u16* __restrict__ encT){
  int ct=blockIdx.x, lt=blockIdx.y, b=blockIdx.z, t=threadIdx.x;
  __shared__ __align__(16) u16 tile[64][72];
  int l0=lt*64, c0=ct*64;
  for(int p=0;p<4;p++){
    int lr=p*16+(t>>4);
    int cc=(t&15)*4;
    float4 v=*(const float4*)&enc[((size_t)b*LK+l0+lr)*C_+c0+cc];
    u16 h0=f2b(v.x),h1=f2b(v.y),h2=f2b(v.z),h3=f2b(v.w);
    ushort4v o; o[0]=h0;o[1]=h1;o[2]=h2;o[3]=h3;
    *(ushort4v*)&encb[((size_t)b*LK+l0+lr)*C_+c0+cc]=o;
    tile[cc+0][lr]=h0; tile[cc+1][lr]=h1; tile[cc+2][lr]=h2; tile[cc+3][lr]=h3;
  }
  __syncthreads();
  for(int p=0;p<2;p++){
    int cr=p*32+(t>>3), loff=(t&7)*8;
    ushort8 w=*(const ushort8*)&tile[cr][loff];
    *(ushort8*)&encT[((size_t)b*C_+c0+cr)*LK+l0+loff]=w;
  }
}

// ---------------- K5: column sums of enc (from encT rows) -------------------
__global__ void k_colsum(const u16* __restrict__ encT, float* __restrict__ encsum){
  int b=blockIdx.x;
  int w=threadIdx.x>>6, lane=threadIdx.x&63;
  int c=blockIdx.y*4+w;
  const u16* row=encT+((size_t)b*C_+c)*LK;
  float s=0.f;
  for(int i=0;i<8;i++){
    ushort8 v=*(const ushort8*)&row[(i*64+lane)*8];
    for(int j=0;j<8;j++) s+=b2f(v[j]);
  }
  for(int off=32;off;off>>=1) s+=__shfl_down(s,off);
  if(lane==0) encsum[b*C_+c]=s;
}

// ---------------- K6: scores S[b][hu][l] = q_effK @ enc^T  (bf16 MFMA) ------
// mt fastest-varying: the 6 blocks sharing one encb tile dispatch consecutively.
__global__ __launch_bounds__(256) void k_scores(const u16* __restrict__ encb,
                                                const u16* __restrict__ qeb,
                                                u16* __restrict__ S){
  int mt=blockIdx.x, nt=blockIdx.y, b=blockIdx.z, t=threadIdx.x;
  __shared__ __align__(16) u16 qe[32][520];
  __shared__ __align__(16) u16 et[256][40];
  int hu0=mt*32, l0=nt*256;
  for(int i=t;i<32*64;i+=256){
    int r=i>>6, cc=(i&63)*8;
    *(ushort8*)&qe[r][cc]=*(const ushort8*)&qeb[(hu0+r)*C_+cc];
  }
  int w=t>>6, lane=t&63;
  int arow=lane&15, kgrp=(lane>>4)*4;
  f32x4 acc[2][4];
  #pragma unroll
  for(int i=0;i<2;i++)
    #pragma unroll
    for(int j=0;j<4;j++) acc[i][j]=(f32x4){0.f,0.f,0.f,0.f};
  for(int kc=0;kc<C_;kc+=32){
    __syncthreads();
    for(int i=t;i<1024;i+=256){
      int l=i>>2, off=(i&3)*8;
      *(ushort8*)&et[l][off]=*(const ushort8*)&encb[((size_t)b*LK+l0+l)*C_+kc+off];
    }
    __syncthreads();
    short8 af0=ldfrag(&qe[arow][kc+kgrp]);
    short8 af1=ldfrag(&qe[16+arow][kc+kgrp]);
    #pragma unroll
    for(int ns=0;ns<4;ns++){
      short8 bf=ldfrag(&et[w*64+ns*16+arow][kgrp]);
      acc[0][ns]=__builtin_amdgcn_mfma_f32_16x16x32_bf16(af0,bf,acc[0][ns],0,0,0);
      acc[1][ns]=__builtin_amdgcn_mfma_f32_16x16x32_bf16(af1,bf,acc[1][ns],0,0,0);
    }
  }
  int dcol=lane&15, drow=(lane>>4)*4;
  #pragma unroll
  for(int ms=0;ms<2;ms++)
    #pragma unroll
    for(int ns=0;ns<4;ns++){
      size_t base=((size_t)b*HUP+hu0+ms*16+drow)*LK + l0 + w*64 + ns*16 + dcol;
      #pragma unroll
      for(int r=0;r<4;r++)
        S[base+(size_t)r*LK]=f2b(acc[ms][ns][r]);
    }
}

// ---------------- K7: row softmax over l (scale 1/8), in place --------------
__global__ void k_softmax(u16* __restrict__ S){
  int hu=blockIdx.x, b=blockIdx.y, t=threadIdx.x;
  u16* row=S+((size_t)b*HUP+hu)*LK;
  __shared__ float red[8];
  __shared__ float red2[8];
  float v[16];
  ushort8 r0=*(const ushort8*)&row[t*16];
  ushort8 r1=*(const ushort8*)&row[t*16+8];
  #pragma unroll
  for(int j=0;j<8;j++){ v[j]=b2f(r0[j]); v[8+j]=b2f(r1[j]); }
  float mx=-1e30f;
  #pragma unroll
  for(int j=0;j<16;j++) mx=fmaxf(mx,v[j]);
  for(int off=32;off;off>>=1) mx=fmaxf(mx,__shfl_xor(mx,off));
  int w=t>>6, lane=t&63;
  if(lane==0) red[w]=mx;
  __syncthreads();
  mx=fmaxf(fmaxf(red[0],red[1]),fmaxf(red[2],red[3]));
  const float scale=0.125f;
  float sm=0.f;
  #pragma unroll
  for(int j=0;j<16;j++){ v[j]=__expf((v[j]-mx)*scale); sm+=v[j]; }
  for(int off=32;off;off>>=1) sm+=__shfl_xor(sm,off);
  if(lane==0) red2[w]=sm;
  __syncthreads();
  sm=red2[0]+red2[1]+red2[2]+red2[3];
  float inv=1.f/sm;
  ushort8 o0,o1;
  #pragma unroll
  for(int j=0;j<8;j++){ o0[j]=f2b(v[j]*inv); o1[j]=f2b(v[8+j]*inv); }
  *(ushort8*)&row[t*16]=o0;
  *(ushort8*)&row[t*16+8]=o1;
}

// ---------------- K8: ctxA[b][hu][c] = attn @ enc  (bf16 MFMA, K=4096) ------
// mt fastest-varying: the 4 blocks sharing one encT c-tile dispatch consecutively.
__global__ __launch_bounds__(256) void k_pv(const u16* __restrict__ S,
                                            const u16* __restrict__ encT,
                                            float* __restrict__ ctxA){
  int mt=blockIdx.x, nt=blockIdx.y, b=blockIdx.z, t=threadIdx.x;
  __shared__ __align__(16) u16 pa[48][72];
  __shared__ __align__(16) u16 et[128][72];
  int hu0=mt*48, c0=nt*128;
  int w=t>>6, lane=t&63;
  int arow=lane&15, kgrp=(lane>>4)*4;
  f32x4 acc[3][2];
  #pragma unroll
  for(int i=0;i<3;i++)
    #pragma unroll
    for(int j=0;j<2;j++) acc[i][j]=(f32x4){0.f,0.f,0.f,0.f};
  for(int l0=0;l0<LK;l0+=64){
    __syncthreads();
    for(int i=t;i<384;i+=256){
      int r=i>>3, off=(i&7)*8;
      *(ushort8*)&pa[r][off]=*(const ushort8*)&S[((size_t)b*HUP+hu0+r)*LK+l0+off];
    }
    for(int i=t;i<1024;i+=256){
      int r=i>>3, off=(i&7)*8;
      *(ushort8*)&et[r][off]=*(const ushort8*)&encT[((size_t)b*C_+c0+r)*LK+l0+off];
    }
    __syncthreads();
    #pragma unroll
    for(int ks=0;ks<2;ks++){
      short8 af0=ldfrag(&pa[arow][ks*32+kgrp]);
      short8 af1=ldfrag(&pa[16+arow][ks*32+kgrp]);
      short8 af2=ldfrag(&pa[32+arow][ks*32+kgrp]);
      #pragma unroll
      for(int ns=0;ns<2;ns++){
        short8 bf=ldfrag(&et[w*32+ns*16+arow][ks*32+kgrp]);
        acc[0][ns]=__builtin_amdgcn_mfma_f32_16x16x32_bf16(af0,bf,acc[0][ns],0,0,0);
        acc[1][ns]=__builtin_amdgcn_mfma_f32_16x16x32_bf16(af1,bf,acc[1][ns],0,0,0);
        acc[2][ns]=__builtin_amdgcn_mfma_f32_16x16x32_bf16(af2,bf,acc[2][ns],0,0,0);
      }
    }
  }
  int dcol=lane&15, drow=(lane>>4)*4;
  #pragma unroll
  for(int m=0;m<3;m++)
    #pragma unroll
    for(int ns=0;ns<2;ns++)
      #pragma unroll
      for(int r=0;r<4;r++){
        int hu=hu0+m*16+drow+r, c=c0+w*32+ns*16+dcol;
        ctxA[((size_t)b*HUP+hu)*C_+c]=acc[m][ns][r];
      }
}

// ---------------- K9: ctx[b][u][hd] = (sel? ctxA : enc_mean) @ Wv + bv ------
__global__ void k_ctxproj(const float* __restrict__ ctxA, const float* __restrict__ encsum,
                          const unsigned* __restrict__ selmask, const float* __restrict__ Wv,
                          const float* __restrict__ bv, float* __restrict__ ctx){
  int u=blockIdx.x, b=blockIdx.y, t=threadIdx.x;
  __shared__ float R[H_][C_];
  for(int h=0;h<H_;h++){
    bool sel=(selmask[b*H_+h]>>u)&1u;
    const float* src=sel? &ctxA[((size_t)b*HUP+h*U_+u)*C_] : &encsum[b*C_];
    float sc=sel? 1.f : (1.f/(float)LK);
    for(int c=t;c<C_;c+=256) R[h][c]=src[c]*sc;
  }
  __syncthreads();
  for(int hd=t;hd<C_;hd+=256){
    int h=hd>>6;
    float a=0.f;
    for(int c=0;c<C_;c++) a+=R[h][c]*Wv[(size_t)c*C_+hd];
    ctx[((size_t)(b*U_+u))*C_+hd]=a+bv[hd];
  }
}

// ---------------- K10: attn_out = ctx@Wo+bo ; x = LN(2*attn_out); + xb bf16 -
__global__ void k_wo_ln1(const float* __restrict__ ctx, const float* __restrict__ Wo,
                         const float* __restrict__ bo, const float* __restrict__ g1,
                         const float* __restrict__ be1, float* __restrict__ x,
                         u16* __restrict__ xb){
  int u=blockIdx.x, b=blockIdx.y, t=threadIdx.x;
  __shared__ float row[C_];
  __shared__ float red[8];
  size_t r0=(size_t)(b*U_+u)*C_;
  for(int c=t;c<C_;c+=256) row[c]=ctx[r0+c];
  __syncthreads();
  float a0=0.f,a1=0.f;
  for(int c=0;c<C_;c++){
    float rv=row[c];
    a0+=rv*Wo[(size_t)c*C_+t];
    a1+=rv*Wo[(size_t)c*C_+t+256];
  }
  a0=2.f*(a0+bo[t]); a1=2.f*(a1+bo[t+256]);
  float mu=blocksum(a0+a1,red)*(1.f/(float)C_);
  float d0=a0-mu, d1=a1-mu;
  float var=blocksum(d0*d0+d1*d1,red)*(1.f/(float)C_);
  float rs=rsqrtf(var+EPSF);
  float x0=d0*rs*g1[t]+be1[t];
  float x1=d1*rs*g1[t+256]+be1[t+256];
  x[r0+t]=x0;
  x[r0+t+256]=x1;
  xb[r0+t]=f2b(x0);
  xb[r0+t+256]=f2b(x1);
}

// ---------------- K10b: W1,W2 fp32 -> bf16 (one shot) -----------------------
__global__ void k_convw(const float* __restrict__ W1, const float* __restrict__ W2,
                        u16* __restrict__ W1b, u16* __restrict__ W2b){
  size_t i=((size_t)blockIdx.x*256+threadIdx.x)*8;
  const float* src; u16* dst;
  const size_t NW=(size_t)DFF*C_;
  if(i<NW){ src=W1; dst=W1b; } else { src=W2; dst=W2b; i-=NW; }
  float4 a=*(const float4*)&src[i];
  float4 b=*(const float4*)&src[i+4];
  ushort8 o;
  o[0]=f2b(a.x);o[1]=f2b(a.y);o[2]=f2b(a.z);o[3]=f2b(a.w);
  o[4]=f2b(b.x);o[5]=f2b(b.y);o[6]=f2b(b.z);o[7]=f2b(b.w);
  *(ushort8*)&dst[i]=o;
}

// ---------------- K11: ff1b = relu(xb @ W1b^T + b1)  bf16 MFMA --------------
// M=704 (22x32), N=2048 (8x256), K=512
__global__ __launch_bounds__(256) void k_ff1m(const u16* __restrict__ xb,
                                              const u16* __restrict__ W1b,
                                              const float* __restrict__ b1,
                                              u16* __restrict__ ff1b){
  int mt=blockIdx.x, ntb=blockIdx.y, t=threadIdx.x;
  __shared__ __align__(16) u16 a_lds[32][520];
  __shared__ __align__(16) u16 et[256][40];
  int m0=mt*32, n0=ntb*256;
  for(int i=t;i<32*64;i+=256){
    int r=i>>6, cc=(i&63)*8;
    *(ushort8*)&a_lds[r][cc]=*(const ushort8*)&xb[(size_t)(m0+r)*C_+cc];
  }
  int w=t>>6, lane=t&63;
  int arow=lane&15, kgrp=(lane>>4)*4;
  f32x4 acc[2][4];
  #pragma unroll
  for(int i=0;i<2;i++)
    #pragma unroll
    for(int j=0;j<4;j++) acc[i][j]=(f32x4){0.f,0.f,0.f,0.f};
  for(int kc=0;kc<C_;kc+=32){
    __syncthreads();
    for(int i=t;i<1024;i+=256){
      int n=i>>2, off=(i&3)*8;
      *(ushort8*)&et[n][off]=*(const ushort8*)&W1b[(size_t)(n0+n)*C_+kc+off];
    }
    __syncthreads();
    short8 af0=ldfrag(&a_lds[arow][kc+kgrp]);
    short8 af1=ldfrag(&a_lds[16+arow][kc+kgrp]);
    #pragma unroll
    for(int ns=0;ns<4;ns++){
      short8 bf=ldfrag(&et[w*64+ns*16+arow][kgrp]);
      acc[0][ns]=__builtin_amdgcn_mfma_f32_16x16x32_bf16(af0,bf,acc[0][ns],0,0,0);
      acc[1][ns]=__builtin_amdgcn_mfma_f32_16x16x32_bf16(af1,bf,acc[1][ns],0,0,0);
    }
  }
  int dcol=lane&15, drow=(lane>>4)*4;
  #pragma unroll
  for(int ms=0;ms<2;ms++)
    #pragma unroll
    for(int ns=0;ns<4;ns++){
      int n=n0+w*64+ns*16+dcol;
      float bb=b1[n];
      #pragma unroll
      for(int r=0;r<4;r++){
        int m=m0+ms*16+drow+r;
        float v=acc[ms][ns][r]+bb;
        ff1b[(size_t)m*DFF+n]=f2b(v>0.f?v:0.f);
      }
    }
}

// ---------------- K12: ff2 += ff1b @ W2b^T  bf16 MFMA, K-split 4 ------------
// M=704 (22x32), N=512 (2x256), K=2048 (4 chunks of 512)
__global__ __launch_bounds__(256) void k_ff2m(const u16* __restrict__ ff1b,
                                              const u16* __restrict__ W2b,
                                              float* __restrict__ out){
  int mt=blockIdx.x, ntb=blockIdx.y, kch=blockIdx.z, t=threadIdx.x;
  __shared__ __align__(16) u16 a_lds[32][520];
  __shared__ __align__(16) u16 et[256][40];
  int m0=mt*32, n0=ntb*256, k0=kch*512;
  for(int i=t;i<32*64;i+=256){
    int r=i>>6, cc=(i&63)*8;
    *(ushort8*)&a_lds[r][cc]=*(const ushort8*)&ff1b[(size_t)(m0+r)*DFF+k0+cc];
  }
  int w=t>>6, lane=t&63;
  int arow=lane&15, kgrp=(lane>>4)*4;
  f32x4 acc[2][4];
  #pragma unroll
  for(int i=0;i<2;i++)
    #pragma unroll
    for(int j=0;j<4;j++) acc[i][j]=(f32x4){0.f,0.f,0.f,0.f};
  for(int kc=0;kc<512;kc+=32){
    __syncthreads();
    for(int i=t;i<1024;i+=256){
      int n=i>>2, off=(i&3)*8;
      *(ushort8*)&et[n][off]=*(const ushort8*)&W2b[(size_t)(n0+n)*DFF+k0+kc+off];
    }
    __syncthreads();
    short8 af0=ldfrag(&a_lds[arow][kc+kgrp]);
    short8 af1=ldfrag(&a_lds[16+arow][kc+kgrp]);
    #pragma unroll
    for(int ns=0;ns<4;ns++){
      short8 bf=ldfrag(&et[w*64+ns*16+arow][kgrp]);
      acc[0][ns]=__builtin_amdgcn_mfma_f32_16x16x32_bf16(af0,bf,acc[0][ns],0,0,0);
      acc[1][ns]=__builtin_amdgcn_mfma_f32_16x16x32_bf16(af1,bf,acc[1][ns],0,0,0);
    }
  }
  int dcol=lane&15, drow=(lane>>4)*4;
  #pragma unroll
  for(int ms=0;ms<2;ms++)
    #pragma unroll
    for(int ns=0;ns<4;ns++){
      int n=n0+w*64+ns*16+dcol;
      #pragma unroll
      for(int r=0;r<4;r++){
        int m=m0+ms*16+drow+r;
        atomicAdd(&out[(size_t)m*C_+n],acc[ms][ns][r]);
      }
    }
}

// ---------------- K13: y = LN(x + ff2 + b2); forecasts = y@Wout + bout ------
__global__ void k_ln2(const float* __restrict__ x, const float* __restrict__ ff2,
                      const float* __restrict__ b2, const float* __restrict__ g2,
                      const float* __restrict__ be2, const float* __restrict__ Wout,
                      const float* __restrict__ bout, float* __restrict__ dout){
  int u=blockIdx.x, b=blockIdx.y, t=threadIdx.x;
  __shared__ float red[8];
  size_t r0=(size_t)(b*U_+u)*C_;
  float s0=x[r0+t]+ff2[r0+t]+b2[t];
  float s1=x[r0+t+256]+ff2[r0+t+256]+b2[t+256];
  float mu=blocksum(s0+s1,red)*(1.f/(float)C_);
  float d0=s0-mu, d1=s1-mu;
  float var=blocksum(d0*d0+d1*d1,red)*(1.f/(float)C_);
  float rs=rsqrtf(var+EPSF);
  float y0=d0*rs*g2[t]+be2[t];
  float y1=d1*rs*g2[t+256]+be2[t+256];
  float* Y=dout+B_*U_;
  Y[r0+t]=y0;
  Y[r0+t+256]=y1;
  float f=blocksum(y0*Wout[t]+y1*Wout[t+256],red);
  if(t==0) dout[b*U_+u]=f+bout[0];
}

extern "C" void kernel_launch(void* const* d_in, const int* in_sizes, int n_in,
                              void* d_out, int out_size, void* d_ws, size_t ws_size,
                              hipStream_t stream){
  (void)in_sizes;(void)n_in;(void)out_size;(void)ws_size;
  const float* enc =(const float*)d_in[0];
  const float* Wq  =(const float*)d_in[1];
  const float* bq  =(const float*)d_in[2];
  const float* Wk  =(const float*)d_in[3];
  // d_in[4] = bk: provably cancels (row-constant shift, softmax/max-mean invariant)
  const float* Wv  =(const float*)d_in[5];
  const float* bv  =(const float*)d_in[6];
  const float* Wo  =(const float*)d_in[7];
  const float* bo  =(const float*)d_in[8];
  const float* W1  =(const float*)d_in[9];
  const float* b1  =(const float*)d_in[10];
  const float* W2  =(const float*)d_in[11];
  const float* b2  =(const float*)d_in[12];
  const float* g1  =(const float*)d_in[13];
  const float* be1 =(const float*)d_in[14];
  const float* g2  =(const float*)d_in[15];
  const float* be2 =(const float*)d_in[16];
  const float* Wout=(const float*)d_in[17];
  const float* bout=(const float*)d_in[18];

  char* ws=(char*)d_ws;
  float*    q      =(float*)   (ws+0);           //  45,056 B
  float*    qef    =(float*)   (ws+45056);       // 393,216 B (192 rows, pad zeroed)
  u16*      qeb    =(u16*)     (ws+438272);      // 196,608 B
  unsigned* selmask=(unsigned*)(ws+634880);      //   1,024 B
  float*    encsum =(float*)   (ws+635904);      //  65,536 B
  u16*      encb   =(u16*)     (ws+701440);      // 134,217,728 B (dead after k_scores)
  u16*      encT   =(u16*)     (ws+134919168);   // 134,217,728 B
  u16*      S      =(u16*)     (ws+269136896);   //  50,331,648 B  (high water ~319.5 MB)
  // overlays into the dead encb region:
  float*    ctxA   =(float*)   (ws+701440);      //  12,582,912 B
  float*    ctx    =(float*)   (ws+13284352);    //   1,441,792 B
  float*    x      =(float*)   (ws+14726144);    //   1,441,792 B
  u16*      ff1b   =(u16*)     (ws+16167936);    //   2,883,584 B
  float*    ff2    =(float*)   (ws+21935104);    //   1,441,792 B
  u16*      W1b    =(u16*)     (ws+23376896);    //   2,097,152 B
  u16*      W2b    =(u16*)     (ws+25474048);    //   2,097,152 B
  u16*      xb     =(u16*)     (ws+27571200);    //     720,896 B

  hipLaunchKernelGGL(k_prep_q, dim3(22),      dim3(256),0,stream, Wq,bq,q);
  hipLaunchKernelGGL(k_qeff,   dim3(192),     dim3(256),0,stream, q,Wk,qef,qeb);
  hipLaunchKernelGGL(k_sample, dim3(256),     dim3(256),0,stream, enc,qef,selmask);
  hipLaunchKernelGGL(k_convert,dim3(8,64,32), dim3(256),0,stream, enc,encb,encT);
  hipLaunchKernelGGL(k_colsum, dim3(32,128),  dim3(256),0,stream, encT,encsum);
  hipLaunchKernelGGL(k_scores, dim3(6,16,32), dim3(256),0,stream, encb,qeb,S);
  hipLaunchKernelGGL(k_softmax,dim3(192,32),  dim3(256),0,stream, S);
  hipLaunchKernelGGL(k_pv,     dim3(4,4,32),  dim3(256),0,stream, S,encT,ctxA);
  hipLaunchKernelGGL(k_ctxproj,dim3(22,32),   dim3(256),0,stream, ctxA,encsum,selmask,Wv,bv,ctx);
  hipLaunchKernelGGL(k_convw,  dim3(1024),    dim3(256),0,stream, W1,W2,W1b,W2b);
  hipLaunchKernelGGL(k_wo_ln1, dim3(22,32),   dim3(256),0,stream, ctx,Wo,bo,g1,be1,x,xb);
  hipLaunchKernelGGL(k_ff1m,   dim3(22,8),    dim3(256),0,stream, xb,W1b,b1,ff1b);
  hipMemsetAsync(ff2,0,1441792,stream);
  hipLaunchKernelGGL(k_ff2m,   dim3(22,2,4),  dim3(256),0,stream, ff1b,W2b,ff2);
  hipLaunchKernelGGL(k_ln2,    dim3(22,32),   dim3(256),0,stream, x,ff2,b2,g2,be2,Wout,bout,(float*)d_out);
}

// Round 5
// 1053.610 us; speedup vs baseline: 1.2603x; 1.0017x over previous
//
#include <hip/hip_runtime.h>
#include <math.h>

#define B_ 32
#define LK 4096
#define C_ 512
#define H_ 8
#define DH 64
#define U_ 22
#define HU 176
#define HUP 192
#define SK 45
#define NTOP 20
#define DFF 2048
#define EPSF 1e-5f

typedef unsigned short u16;
typedef __attribute__((ext_vector_type(8))) short short8;
typedef __attribute__((ext_vector_type(4))) short short4v;
typedef __attribute__((ext_vector_type(8))) unsigned short ushort8;
typedef __attribute__((ext_vector_type(4))) unsigned short ushort4v;
typedef __attribute__((ext_vector_type(4))) float f32x4;

__device__ __forceinline__ u16 f2b(float f){
  union{float f;unsigned u;} v; v.f=f;
  unsigned r=(v.u + 0x7FFFu + ((v.u>>16)&1u))>>16;
  return (u16)r;
}
__device__ __forceinline__ float b2f(u16 h){
  union{unsigned u;float f;} v; v.u=((unsigned)h)<<16; return v.f;
}
// Build an 8-elem bf16 fragment: elems 0-3 at p[0..3], elems 4-7 at p[16..19].
// Same pattern for A and B => result invariant to HW's internal k-permutation.
__device__ __forceinline__ short8 ldfrag(const u16* p){
  short4v lo=*(const short4v*)p;
  short4v hi=*(const short4v*)(p+16);
  short8 r;
  r[0]=lo[0];r[1]=lo[1];r[2]=lo[2];r[3]=lo[3];
  r[4]=hi[0];r[5]=hi[1];r[6]=hi[2];r[7]=hi[3];
  return r;
}
__device__ __forceinline__ float blocksum(float v, float* red){
  for(int off=32;off;off>>=1) v+=__shfl_xor(v,off);
  int w=threadIdx.x>>6, lane=threadIdx.x&63;
  if(lane==0) red[w]=v;
  __syncthreads();
  float r=red[0]+red[1]+red[2]+red[3];
  __syncthreads();
  return r;
}

// ---------------- K1: positional encoding -> q = pe@Wq + bq  (22 x 512) -----
__global__ void k_prep_q(const float* __restrict__ Wq, const float* __restrict__ bq,
                         float* __restrict__ q){
  __shared__ float pe[C_];
  int u=blockIdx.x, t=threadIdx.x;
  float lg = logf(10000.0f)/(float)C_;
  for(int c=t;c<C_;c+=256){
    int i=c>>1;
    float arg=(float)u*expf(-(float)(2*i)*lg);
    pe[c]=(c&1)?cosf(arg):sinf(arg);
  }
  __syncthreads();
  for(int col=t;col<C_;col+=256){
    float acc=0.f;
    for(int c=0;c<C_;c++) acc+=pe[c]*Wq[c*C_+col];
    q[u*C_+col]=acc+bq[col];
  }
}

// ---------------- K2: q_effK[hu][c] = sum_d q[u][h*64+d]*Wk[c][h*64+d] ------
__global__ void k_qeff(const float* __restrict__ q, const float* __restrict__ Wk,
                       float* __restrict__ qef, u16* __restrict__ qeb){
  int hu=blockIdx.x, t=threadIdx.x;
  int h=hu/U_, u=hu-h*U_;
  __shared__ float qr[DH];
  bool valid=(hu<HU);
  if(t<DH) qr[t]=valid? q[u*C_+h*DH+t] : 0.f;
  __syncthreads();
  for(int c=t;c<C_;c+=256){
    float acc=0.f;
    if(valid){
      const float* wrow=Wk+(size_t)c*C_+h*DH;
      for(int d=0;d<DH;d++) acc+=qr[d]*wrow[d];
    }
    qef[hu*C_+c]=acc;
    qeb[hu*C_+c]=f2b(acc);
  }
}

// ---------------- K3: sampled scores -> M -> top-20 mask (fp32 exact path) --
__global__ void k_sample(const float* __restrict__ enc, const float* __restrict__ qef,
                         unsigned* __restrict__ selmask){
  int bh=blockIdx.x, t=threadIdx.x;
  int b=bh>>3, h=bh&7;
  __shared__ float es[SK][132];
  __shared__ float qe[U_][132];
  __shared__ float qk[U_][SK+3];
  __shared__ float Mv[U_];
  float acc[4]={0.f,0.f,0.f,0.f};
  for(int c0=0;c0<C_;c0+=128){
    __syncthreads();
    for(int i=t;i<SK*128;i+=256){
      int ks=i>>7, c=i&127;
      int row=(ks*LK)/SK;
      es[ks][c]=enc[((size_t)b*LK+row)*C_+c0+c];
    }
    for(int i=t;i<U_*128;i+=256){
      int u=i>>7, c=i&127;
      qe[u][c]=qef[(h*U_+u)*C_+c0+c];
    }
    __syncthreads();
    for(int dd=0;dd<4;dd++){
      int d=t+dd*256;
      if(d<U_*SK){
        int u=d/SK, ks=d-u*SK;
        float s=0.f;
        for(int c=0;c<128;c++) s+=qe[u][c]*es[ks][c];
        acc[dd]+=s;
      }
    }
  }
  for(int dd=0;dd<4;dd++){
    int d=t+dd*256;
    if(d<U_*SK){ int u=d/SK, ks=d-u*SK; qk[u][ks]=acc[dd]; }
  }
  __syncthreads();
  if(t<U_){
    float mx=-1e30f, sm=0.f;
    for(int ks=0;ks<SK;ks++){ float v=qk[t][ks]; mx=fmaxf(mx,v); sm+=v; }
    Mv[t]=mx-sm/(float)SK;
  }
  __syncthreads();
  if(t<64){
    bool sel=false;
    if(t<U_){
      float m=Mv[t]; int rank=0;
      for(int u2=0;u2<U_;u2++){
        float o=Mv[u2];
        if(o>m || (o==m && u2<t)) rank++;
      }
      sel=(rank<NTOP);
    }
    unsigned long long bal=__ballot(sel);
    if(t==0) selmask[bh]=(unsigned)(bal&0x3FFFFFull);
  }
}

// ---------------- K4: enc fp32 -> enc_bf16 [l][c]  AND  encT_bf16 [c][l] ----
__global__ void k_convert(const float* __restrict__ enc, u16* __restrict__ encb,
                          u16* __restrict__ encT){
  int ct=blockIdx.x, lt=blockIdx.y, b=blockIdx.z, t=threadIdx.x;
  __shared__ __align__(16) u16 tile[64][72];
  int l0=lt*64, c0=ct*64;
  for(int p=0;p<4;p++){
    int lr=p*16+(t>>4);
    int cc=(t&15)*4;
    float4 v=*(const float4*)&enc[((size_t)b*LK+l0+lr)*C_+c0+cc];
    u16 h0=f2b(v.x),h1=f2b(v.y),h2=f2b(v.z),h3=f2b(v.w);
    ushort4v o; o[0]=h0;o[1]=h1;o[2]=h2;o[3]=h3;
    *(ushort4v*)&encb[((size_t)b*LK+l0+lr)*C_+c0+cc]=o;
    tile[cc+0][lr]=h0; tile[cc+1][lr]=h1; tile[cc+2][lr]=h2; tile[cc+3][lr]=h3;
  }
  __syncthreads();
  for(int p=0;p<2;p++){
    int cr=p*32+(t>>3), loff=(t&7)*8;
    ushort8 w=*(const ushort8*)&tile[cr][loff];
    *(ushort8*)&encT[((size_t)b*C_+c0+cr)*LK+l0+loff]=w;
  }
}

// ---------------- K5: column sums of enc (from encT rows) -------------------
__global__ void k_colsum(const u16* __restrict__ encT, float* __restrict__ encsum){
  int b=blockIdx.x;
  int w=threadIdx.x>>6, lane=threadIdx.x&63;
  int c=blockIdx.y*4+w;
  const u16* row=encT+((size_t)b*C_+c)*LK;
  float s=0.f;
  for(int i=0;i<8;i++){
    ushort8 v=*(const ushort8*)&row[(i*64+lane)*8];
    for(int j=0;j<8;j++) s+=b2f(v[j]);
  }
  for(int off=32;off;off>>=1) s+=__shfl_down(s,off);
  if(lane==0) encsum[b*C_+c]=s;
}

// ---------------- K6: scores S[b][hu][l] = q_effK @ enc^T  (bf16 MFMA) ------
// Per-kc A staging: LDS 23KB -> ~7 blocks/CU for latency hiding.
__global__ __launch_bounds__(256) void k_scores(const u16* __restrict__ encb,
                                                const u16* __restrict__ qeb,
                                                u16* __restrict__ S){
  int mt=blockIdx.x, nt=blockIdx.y, b=blockIdx.z, t=threadIdx.x;
  __shared__ __align__(16) u16 qa[32][40];
  __shared__ __align__(16) u16 et[256][40];
  int hu0=mt*32, l0=nt*256;
  int w=t>>6, lane=t&63;
  int arow=lane&15, kgrp=(lane>>4)*4;
  f32x4 acc[2][4];
  #pragma unroll
  for(int i=0;i<2;i++)
    #pragma unroll
    for(int j=0;j<4;j++) acc[i][j]=(f32x4){0.f,0.f,0.f,0.f};
  for(int kc=0;kc<C_;kc+=32){
    __syncthreads();
    if(t<128){
      int r=t>>2, off=(t&3)*8;
      *(ushort8*)&qa[r][off]=*(const ushort8*)&qeb[(hu0+r)*C_+kc+off];
    }
    for(int i=t;i<1024;i+=256){
      int l=i>>2, off=(i&3)*8;
      *(ushort8*)&et[l][off]=*(const ushort8*)&encb[((size_t)b*LK+l0+l)*C_+kc+off];
    }
    __syncthreads();
    short8 af0=ldfrag(&qa[arow][kgrp]);
    short8 af1=ldfrag(&qa[16+arow][kgrp]);
    #pragma unroll
    for(int ns=0;ns<4;ns++){
      short8 bf=ldfrag(&et[w*64+ns*16+arow][kgrp]);
      acc[0][ns]=__builtin_amdgcn_mfma_f32_16x16x32_bf16(af0,bf,acc[0][ns],0,0,0);
      acc[1][ns]=__builtin_amdgcn_mfma_f32_16x16x32_bf16(af1,bf,acc[1][ns],0,0,0);
    }
  }
  int dcol=lane&15, drow=(lane>>4)*4;
  #pragma unroll
  for(int ms=0;ms<2;ms++)
    #pragma unroll
    for(int ns=0;ns<4;ns++){
      size_t base=((size_t)b*HUP+hu0+ms*16+drow)*LK + l0 + w*64 + ns*16 + dcol;
      #pragma unroll
      for(int r=0;r<4;r++)
        S[base+(size_t)r*LK]=f2b(acc[ms][ns][r]);
    }
}

// ---------------- K7: row softmax over l (scale 1/8), in place --------------
__global__ void k_softmax(u16* __restrict__ S){
  int hu=blockIdx.x, b=blockIdx.y, t=threadIdx.x;
  u16* row=S+((size_t)b*HUP+hu)*LK;
  __shared__ float red[8];
  __shared__ float red2[8];
  float v[16];
  ushort8 r0=*(const ushort8*)&row[t*16];
  ushort8 r1=*(const ushort8*)&row[t*16+8];
  #pragma unroll
  for(int j=0;j<8;j++){ v[j]=b2f(r0[j]); v[8+j]=b2f(r1[j]); }
  float mx=-1e30f;
  #pragma unroll
  for(int j=0;j<16;j++) mx=fmaxf(mx,v[j]);
  for(int off=32;off;off>>=1) mx=fmaxf(mx,__shfl_xor(mx,off));
  int w=t>>6, lane=t&63;
  if(lane==0) red[w]=mx;
  __syncthreads();
  mx=fmaxf(fmaxf(red[0],red[1]),fmaxf(red[2],red[3]));
  const float scale=0.125f;
  float sm=0.f;
  #pragma unroll
  for(int j=0;j<16;j++){ v[j]=__expf((v[j]-mx)*scale); sm+=v[j]; }
  for(int off=32;off;off>>=1) sm+=__shfl_xor(sm,off);
  if(lane==0) red2[w]=sm;
  __syncthreads();
  sm=red2[0]+red2[1]+red2[2]+red2[3];
  float inv=1.f/sm;
  ushort8 o0,o1;
  #pragma unroll
  for(int j=0;j<8;j++){ o0[j]=f2b(v[j]*inv); o1[j]=f2b(v[8+j]*inv); }
  *(ushort8*)&row[t*16]=o0;
  *(ushort8*)&row[t*16+8]=o1;
}

// ---------------- K8: ctxA[b][hu][c] += attn @ enc  (bf16 MFMA, K-split 4) --
// 2048 blocks (6/CU LDS-resident) for latency hiding; f32 atomicAdd epilogue.
__global__ __launch_bounds__(256) void k_pv(const u16* __restrict__ S,
                                            const u16* __restrict__ encT,
                                            float* __restrict__ ctxA){
  int mt=blockIdx.x, nt=blockIdx.y, bz=blockIdx.z, t=threadIdx.x;
  int b=bz>>2, kch=bz&3;
  __shared__ __align__(16) u16 pa[48][72];
  __shared__ __align__(16) u16 et[128][72];
  int hu0=mt*48, c0=nt*128;
  int w=t>>6, lane=t&63;
  int arow=lane&15, kgrp=(lane>>4)*4;
  f32x4 acc[3][2];
  #pragma unroll
  for(int i=0;i<3;i++)
    #pragma unroll
    for(int j=0;j<2;j++) acc[i][j]=(f32x4){0.f,0.f,0.f,0.f};
  int lbase=kch*1024;
  for(int l0=lbase;l0<lbase+1024;l0+=64){
    __syncthreads();
    for(int i=t;i<384;i+=256){
      int r=i>>3, off=(i&7)*8;
      *(ushort8*)&pa[r][off]=*(const ushort8*)&S[((size_t)b*HUP+hu0+r)*LK+l0+off];
    }
    for(int i=t;i<1024;i+=256){
      int r=i>>3, off=(i&7)*8;
      *(ushort8*)&et[r][off]=*(const ushort8*)&encT[((size_t)b*C_+c0+r)*LK+l0+off];
    }
    __syncthreads();
    #pragma unroll
    for(int ks=0;ks<2;ks++){
      short8 af0=ldfrag(&pa[arow][ks*32+kgrp]);
      short8 af1=ldfrag(&pa[16+arow][ks*32+kgrp]);
      short8 af2=ldfrag(&pa[32+arow][ks*32+kgrp]);
      #pragma unroll
      for(int ns=0;ns<2;ns++){
        short8 bf=ldfrag(&et[w*32+ns*16+arow][ks*32+kgrp]);
        acc[0][ns]=__builtin_amdgcn_mfma_f32_16x16x32_bf16(af0,bf,acc[0][ns],0,0,0);
        acc[1][ns]=__builtin_amdgcn_mfma_f32_16x16x32_bf16(af1,bf,acc[1][ns],0,0,0);
        acc[2][ns]=__builtin_amdgcn_mfma_f32_16x16x32_bf16(af2,bf,acc[2][ns],0,0,0);
      }
    }
  }
  int dcol=lane&15, drow=(lane>>4)*4;
  #pragma unroll
  for(int m=0;m<3;m++)
    #pragma unroll
    for(int ns=0;ns<2;ns++)
      #pragma unroll
      for(int r=0;r<4;r++){
        int hu=hu0+m*16+drow+r, c=c0+w*32+ns*16+dcol;
        atomicAdd(&ctxA[((size_t)b*HUP+hu)*C_+c],acc[m][ns][r]);
      }
}

// ---------------- K9: ctx[b][u][hd] = (sel? ctxA : enc_mean) @ Wv + bv ------
__global__ void k_ctxproj(const float* __restrict__ ctxA, const float* __restrict__ encsum,
                          const unsigned* __restrict__ selmask, const float* __restrict__ Wv,
                          const float* __restrict__ bv, float* __restrict__ ctx){
  int u=blockIdx.x, b=blockIdx.y, t=threadIdx.x;
  __shared__ float R[H_][C_];
  for(int h=0;h<H_;h++){
    bool sel=(selmask[b*H_+h]>>u)&1u;
    const float* src=sel? &ctxA[((size_t)b*HUP+h*U_+u)*C_] : &encsum[b*C_];
    float sc=sel? 1.f : (1.f/(float)LK);
    for(int c=t;c<C_;c+=256) R[h][c]=src[c]*sc;
  }
  __syncthreads();
  for(int hd=t;hd<C_;hd+=256){
    int h=hd>>6;
    float a=0.f;
    for(int c=0;c<C_;c++) a+=R[h][c]*Wv[(size_t)c*C_+hd];
    ctx[((size_t)(b*U_+u))*C_+hd]=a+bv[hd];
  }
}

// ---------------- K10: attn_out = ctx@Wo+bo ; x = LN(2*attn_out); + xb bf16 -
__global__ void k_wo_ln1(const float* __restrict__ ctx, const float* __restrict__ Wo,
                         const float* __restrict__ bo, const float* __restrict__ g1,
                         const float* __restrict__ be1, float* __restrict__ x,
                         u16* __restrict__ xb){
  int u=blockIdx.x, b=blockIdx.y, t=threadIdx.x;
  __shared__ float row[C_];
  __shared__ float red[8];
  size_t r0=(size_t)(b*U_+u)*C_;
  for(int c=t;c<C_;c+=256) row[c]=ctx[r0+c];
  __syncthreads();
  float a0=0.f,a1=0.f;
  for(int c=0;c<C_;c++){
    float rv=row[c];
    a0+=rv*Wo[(size_t)c*C_+t];
    a1+=rv*Wo[(size_t)c*C_+t+256];
  }
  a0=2.f*(a0+bo[t]); a1=2.f*(a1+bo[t+256]);
  float mu=blocksum(a0+a1,red)*(1.f/(float)C_);
  float d0=a0-mu, d1=a1-mu;
  float var=blocksum(d0*d0+d1*d1,red)*(1.f/(float)C_);
  float rs=rsqrtf(var+EPSF);
  float x0=d0*rs*g1[t]+be1[t];
  float x1=d1*rs*g1[t+256]+be1[t+256];
  x[r0+t]=x0;
  x[r0+t+256]=x1;
  xb[r0+t]=f2b(x0);
  xb[r0+t+256]=f2b(x1);
}

// ---------------- K10b: W1,W2 fp32 -> bf16 (one shot) -----------------------
__global__ void k_convw(const float* __restrict__ W1, const float* __restrict__ W2,
                        u16* __restrict__ W1b, u16* __restrict__ W2b){
  size_t i=((size_t)blockIdx.x*256+threadIdx.x)*8;
  const float* src; u16* dst;
  const size_t NW=(size_t)DFF*C_;
  if(i<NW){ src=W1; dst=W1b; } else { src=W2; dst=W2b; i-=NW; }
  float4 a=*(const float4*)&src[i];
  float4 b=*(const float4*)&src[i+4];
  ushort8 o;
  o[0]=f2b(a.x);o[1]=f2b(a.y);o[2]=f2b(a.z);o[3]=f2b(a.w);
  o[4]=f2b(b.x);o[5]=f2b(b.y);o[6]=f2b(b.z);o[7]=f2b(b.w);
  *(ushort8*)&dst[i]=o;
}

// ---------------- K11: ff1b = relu(xb @ W1b^T + b1)  bf16 MFMA --------------
// M=704 (22x32), N=2048 (8x256), K=512
__global__ __launch_bounds__(256) void k_ff1m(const u16* __restrict__ xb,
                                              const u16* __restrict__ W1b,
                                              const float* __restrict__ b1,
                                              u16* __restrict__ ff1b){
  int mt=blockIdx.x, ntb=blockIdx.y, t=threadIdx.x;
  __shared__ __align__(16) u16 a_lds[32][520];
  __shared__ __align__(16) u16 et[256][40];
  int m0=mt*32, n0=ntb*256;
  for(int i=t;i<32*64;i+=256){
    int r=i>>6, cc=(i&63)*8;
    *(ushort8*)&a_lds[r][cc]=*(const ushort8*)&xb[(size_t)(m0+r)*C_+cc];
  }
  int w=t>>6, lane=t&63;
  int arow=lane&15, kgrp=(lane>>4)*4;
  f32x4 acc[2][4];
  #pragma unroll
  for(int i=0;i<2;i++)
    #pragma unroll
    for(int j=0;j<4;j++) acc[i][j]=(f32x4){0.f,0.f,0.f,0.f};
  for(int kc=0;kc<C_;kc+=32){
    __syncthreads();
    for(int i=t;i<1024;i+=256){
      int n=i>>2, off=(i&3)*8;
      *(ushort8*)&et[n][off]=*(const ushort8*)&W1b[(size_t)(n0+n)*C_+kc+off];
    }
    __syncthreads();
    short8 af0=ldfrag(&a_lds[arow][kc+kgrp]);
    short8 af1=ldfrag(&a_lds[16+arow][kc+kgrp]);
    #pragma unroll
    for(int ns=0;ns<4;ns++){
      short8 bf=ldfrag(&et[w*64+ns*16+arow][kgrp]);
      acc[0][ns]=__builtin_amdgcn_mfma_f32_16x16x32_bf16(af0,bf,acc[0][ns],0,0,0);
      acc[1][ns]=__builtin_amdgcn_mfma_f32_16x16x32_bf16(af1,bf,acc[1][ns],0,0,0);
    }
  }
  int dcol=lane&15, drow=(lane>>4)*4;
  #pragma unroll
  for(int ms=0;ms<2;ms++)
    #pragma unroll
    for(int ns=0;ns<4;ns++){
      int n=n0+w*64+ns*16+dcol;
      float bb=b1[n];
      #pragma unroll
      for(int r=0;r<4;r++){
        int m=m0+ms*16+drow+r;
        float v=acc[ms][ns][r]+bb;
        ff1b[(size_t)m*DFF+n]=f2b(v>0.f?v:0.f);
      }
    }
}

// ---------------- K12: ff2 += ff1b @ W2b^T  bf16 MFMA, K-split 4 ------------
// M=704 (22x32), N=512 (2x256), K=2048 (4 chunks of 512)
__global__ __launch_bounds__(256) void k_ff2m(const u16* __restrict__ ff1b,
                                              const u16* __restrict__ W2b,
                                              float* __restrict__ out){
  int mt=blockIdx.x, ntb=blockIdx.y, kch=blockIdx.z, t=threadIdx.x;
  __shared__ __align__(16) u16 a_lds[32][520];
  __shared__ __align__(16) u16 et[256][40];
  int m0=mt*32, n0=ntb*256, k0=kch*512;
  for(int i=t;i<32*64;i+=256){
    int r=i>>6, cc=(i&63)*8;
    *(ushort8*)&a_lds[r][cc]=*(const ushort8*)&ff1b[(size_t)(m0+r)*DFF+k0+cc];
  }
  int w=t>>6, lane=t&63;
  int arow=lane&15, kgrp=(lane>>4)*4;
  f32x4 acc[2][4];
  #pragma unroll
  for(int i=0;i<2;i++)
    #pragma unroll
    for(int j=0;j<4;j++) acc[i][j]=(f32x4){0.f,0.f,0.f,0.f};
  for(int kc=0;kc<512;kc+=32){
    __syncthreads();
    for(int i=t;i<1024;i+=256){
      int n=i>>2, off=(i&3)*8;
      *(ushort8*)&et[n][off]=*(const ushort8*)&W2b[(size_t)(n0+n)*DFF+k0+kc+off];
    }
    __syncthreads();
    short8 af0=ldfrag(&a_lds[arow][kc+kgrp]);
    short8 af1=ldfrag(&a_lds[16+arow][kc+kgrp]);
    #pragma unroll
    for(int ns=0;ns<4;ns++){
      short8 bf=ldfrag(&et[w*64+ns*16+arow][kgrp]);
      acc[0][ns]=__builtin_amdgcn_mfma_f32_16x16x32_bf16(af0,bf,acc[0][ns],0,0,0);
      acc[1][ns]=__builtin_amdgcn_mfma_f32_16x16x32_bf16(af1,bf,acc[1][ns],0,0,0);
    }
  }
  int dcol=lane&15, drow=(lane>>4)*4;
  #pragma unroll
  for(int ms=0;ms<2;ms++)
    #pragma unroll
    for(int ns=0;ns<4;ns++){
      int n=n0+w*64+ns*16+dcol;
      #pragma unroll
      for(int r=0;r<4;r++){
        int m=m0+ms*16+drow+r;
        atomicAdd(&out[(size_t)m*C_+n],acc[ms][ns][r]);
      }
    }
}

// ---------------- K13: y = LN(x + ff2 + b2); forecasts = y@Wout + bout ------
__global__ void k_ln2(const float* __restrict__ x, const float* __restrict__ ff2,
                      const float* __restrict__ b2, const float* __restrict__ g2,
                      const float* __restrict__ be2, const float* __restrict__ Wout,
                      const float* __restrict__ bout, float* __restrict__ dout){
  int u=blockIdx.x, b=blockIdx.y, t=threadIdx.x;
  __shared__ float red[8];
  size_t r0=(size_t)(b*U_+u)*C_;
  float s0=x[r0+t]+ff2[r0+t]+b2[t];
  float s1=x[r0+t+256]+ff2[r0+t+256]+b2[t+256];
  float mu=blocksum(s0+s1,red)*(1.f/(float)C_);
  float d0=s0-mu, d1=s1-mu;
  float var=blocksum(d0*d0+d1*d1,red)*(1.f/(float)C_);
  float rs=rsqrtf(var+EPSF);
  float y0=d0*rs*g2[t]+be2[t];
  float y1=d1*rs*g2[t+256]+be2[t+256];
  float* Y=dout+B_*U_;
  Y[r0+t]=y0;
  Y[r0+t+256]=y1;
  float f=blocksum(y0*Wout[t]+y1*Wout[t+256],red);
  if(t==0) dout[b*U_+u]=f+bout[0];
}

extern "C" void kernel_launch(void* const* d_in, const int* in_sizes, int n_in,
                              void* d_out, int out_size, void* d_ws, size_t ws_size,
                              hipStream_t stream){
  (void)in_sizes;(void)n_in;(void)out_size;(void)ws_size;
  const float* enc =(const float*)d_in[0];
  const float* Wq  =(const float*)d_in[1];
  const float* bq  =(const float*)d_in[2];
  const float* Wk  =(const float*)d_in[3];
  // d_in[4] = bk: provably cancels (row-constant shift, softmax/max-mean invariant)
  const float* Wv  =(const float*)d_in[5];
  const float* bv  =(const float*)d_in[6];
  const float* Wo  =(const float*)d_in[7];
  const float* bo  =(const float*)d_in[8];
  const float* W1  =(const float*)d_in[9];
  const float* b1  =(const float*)d_in[10];
  const float* W2  =(const float*)d_in[11];
  const float* b2  =(const float*)d_in[12];
  const float* g1  =(const float*)d_in[13];
  const float* be1 =(const float*)d_in[14];
  const float* g2  =(const float*)d_in[15];
  const float* be2 =(const float*)d_in[16];
  const float* Wout=(const float*)d_in[17];
  const float* bout=(const float*)d_in[18];

  char* ws=(char*)d_ws;
  float*    q      =(float*)   (ws+0);           //  45,056 B
  float*    qef    =(float*)   (ws+45056);       // 393,216 B (192 rows, pad zeroed)
  u16*      qeb    =(u16*)     (ws+438272);      // 196,608 B
  unsigned* selmask=(unsigned*)(ws+634880);      //   1,024 B
  float*    encsum =(float*)   (ws+635904);      //  65,536 B
  u16*      encb   =(u16*)     (ws+701440);      // 134,217,728 B (dead after k_scores)
  u16*      encT   =(u16*)     (ws+134919168);   // 134,217,728 B
  u16*      S      =(u16*)     (ws+269136896);   //  50,331,648 B  (high water ~319.5 MB)
  // overlays into the dead encb region:
  float*    ctxA   =(float*)   (ws+701440);      //  12,582,912 B
  float*    ctx    =(float*)   (ws+13284352);    //   1,441,792 B
  float*    x      =(float*)   (ws+14726144);    //   1,441,792 B
  u16*      ff1b   =(u16*)     (ws+16167936);    //   2,883,584 B
  float*    ff2    =(float*)   (ws+21935104);    //   1,441,792 B
  u16*      W1b    =(u16*)     (ws+23376896);    //   2,097,152 B
  u16*      W2b    =(u16*)     (ws+25474048);    //   2,097,152 B
  u16*      xb     =(u16*)     (ws+27571200);    //     720,896 B

  hipLaunchKernelGGL(k_prep_q, dim3(22),      dim3(256),0,stream, Wq,bq,q);
  hipLaunchKernelGGL(k_qeff,   dim3(192),     dim3(256),0,stream, q,Wk,qef,qeb);
  hipLaunchKernelGGL(k_sample, dim3(256),     dim3(256),0,stream, enc,qef,selmask);
  hipLaunchKernelGGL(k_convert,dim3(8,64,32), dim3(256),0,stream, enc,encb,encT);
  hipLaunchKernelGGL(k_colsum, dim3(32,128),  dim3(256),0,stream, encT,encsum);
  hipLaunchKernelGGL(k_scores, dim3(6,16,32), dim3(256),0,stream, encb,qeb,S);
  hipLaunchKernelGGL(k_softmax,dim3(192,32),  dim3(256),0,stream, S);
  hipMemsetAsync(ctxA,0,12582912,stream);
  hipLaunchKernelGGL(k_pv,     dim3(4,4,128), dim3(256),0,stream, S,encT,ctxA);
  hipLaunchKernelGGL(k_ctxproj,dim3(22,32),   dim3(256),0,stream, ctxA,encsum,selmask,Wv,bv,ctx);
  hipLaunchKernelGGL(k_convw,  dim3(1024),    dim3(256),0,stream, W1,W2,W1b,W2b);
  hipLaunchKernelGGL(k_wo_ln1, dim3(22,32),   dim3(256),0,stream, ctx,Wo,bo,g1,be1,x,xb);
  hipLaunchKernelGGL(k_ff1m,   dim3(22,8),    dim3(256),0,stream, xb,W1b,b1,ff1b);
  hipMemsetAsync(ff2,0,1441792,stream);
  hipLaunchKernelGGL(k_ff2m,   dim3(22,2,4),  dim3(256),0,stream, ff1b,W2b,ff2);
  hipLaunchKernelGGL(k_ln2,    dim3(22,32),   dim3(256),0,stream, x,ff2,b2,g2,be2,Wout,bout,(float*)d_out);
}

// Round 6
// 924.844 us; speedup vs baseline: 1.4358x; 1.1392x over previous
//
#include <hip/hip_runtime.h>
#include <math.h>

#define B_ 32
#define LK 4096
#define C_ 512
#define H_ 8
#define DH 64
#define U_ 22
#define HU 176
#define HUP 192
#define SK 45
#define NTOP 20
#define DFF 2048
#define EPSF 1e-5f

typedef unsigned short u16;
typedef __attribute__((ext_vector_type(8))) short short8;
typedef __attribute__((ext_vector_type(4))) short short4v;
typedef __attribute__((ext_vector_type(8))) unsigned short ushort8;
typedef __attribute__((ext_vector_type(4))) unsigned short ushort4v;
typedef __attribute__((ext_vector_type(4))) float f32x4;

__device__ __forceinline__ u16 f2b(float f){
  union{float f;unsigned u;} v; v.f=f;
  unsigned r=(v.u + 0x7FFFu + ((v.u>>16)&1u))>>16;
  return (u16)r;
}
__device__ __forceinline__ float b2f(u16 h){
  union{unsigned u;float f;} v; v.u=((unsigned)h)<<16; return v.f;
}
// Build an 8-elem bf16 fragment: elems 0-3 at p[0..3], elems 4-7 at p[16..19].
// Same pattern for A and B => result invariant to HW's internal k-permutation.
__device__ __forceinline__ short8 ldfrag(const u16* p){
  short4v lo=*(const short4v*)p;
  short4v hi=*(const short4v*)(p+16);
  short8 r;
  r[0]=lo[0];r[1]=lo[1];r[2]=lo[2];r[3]=lo[3];
  r[4]=hi[0];r[5]=hi[1];r[6]=hi[2];r[7]=hi[3];
  return r;
}
__device__ __forceinline__ float blocksum(float v, float* red){
  for(int off=32;off;off>>=1) v+=__shfl_xor(v,off);
  int w=threadIdx.x>>6, lane=threadIdx.x&63;
  if(lane==0) red[w]=v;
  __syncthreads();
  float r=red[0]+red[1]+red[2]+red[3];
  __syncthreads();
  return r;
}

// ---------------- K1: positional encoding -> q = pe@Wq + bq  (22 x 512) -----
__global__ void k_prep_q(const float* __restrict__ Wq, const float* __restrict__ bq,
                         float* __restrict__ q){
  __shared__ float pe[C_];
  int u=blockIdx.x, t=threadIdx.x;
  float lg = logf(10000.0f)/(float)C_;
  for(int c=t;c<C_;c+=256){
    int i=c>>1;
    float arg=(float)u*expf(-(float)(2*i)*lg);
    pe[c]=(c&1)?cosf(arg):sinf(arg);
  }
  __syncthreads();
  for(int col=t;col<C_;col+=256){
    float acc=0.f;
    for(int c=0;c<C_;c++) acc+=pe[c]*Wq[c*C_+col];
    q[u*C_+col]=acc+bq[col];
  }
}

// ---------------- K2: q_effK[hu][c] = sum_d q[u][h*64+d]*Wk[c][h*64+d] ------
__global__ void k_qeff(const float* __restrict__ q, const float* __restrict__ Wk,
                       float* __restrict__ qef, u16* __restrict__ qeb){
  int hu=blockIdx.x, t=threadIdx.x;
  int h=hu/U_, u=hu-h*U_;
  __shared__ float qr[DH];
  bool valid=(hu<HU);
  if(t<DH) qr[t]=valid? q[u*C_+h*DH+t] : 0.f;
  __syncthreads();
  for(int c=t;c<C_;c+=256){
    float acc=0.f;
    if(valid){
      const float* wrow=Wk+(size_t)c*C_+h*DH;
      for(int d=0;d<DH;d++) acc+=qr[d]*wrow[d];
    }
    qef[hu*C_+c]=acc;
    qeb[hu*C_+c]=f2b(acc);
  }
}

// ---------------- K3: sampled scores -> M -> top-20 mask (fp32 exact path) --
__global__ void k_sample(const float* __restrict__ enc, const float* __restrict__ qef,
                         unsigned* __restrict__ selmask){
  int bh=blockIdx.x, t=threadIdx.x;
  int b=bh>>3, h=bh&7;
  __shared__ float es[SK][132];
  __shared__ float qe[U_][132];
  __shared__ float qk[U_][SK+3];
  __shared__ float Mv[U_];
  float acc[4]={0.f,0.f,0.f,0.f};
  for(int c0=0;c0<C_;c0+=128){
    __syncthreads();
    for(int i=t;i<SK*128;i+=256){
      int ks=i>>7, c=i&127;
      int row=(ks*LK)/SK;
      es[ks][c]=enc[((size_t)b*LK+row)*C_+c0+c];
    }
    for(int i=t;i<U_*128;i+=256){
      int u=i>>7, c=i&127;
      qe[u][c]=qef[(h*U_+u)*C_+c0+c];
    }
    __syncthreads();
    for(int dd=0;dd<4;dd++){
      int d=t+dd*256;
      if(d<U_*SK){
        int u=d/SK, ks=d-u*SK;
        float s=0.f;
        for(int c=0;c<128;c++) s+=qe[u][c]*es[ks][c];
        acc[dd]+=s;
      }
    }
  }
  for(int dd=0;dd<4;dd++){
    int d=t+dd*256;
    if(d<U_*SK){ int u=d/SK, ks=d-u*SK; qk[u][ks]=acc[dd]; }
  }
  __syncthreads();
  if(t<U_){
    float mx=-1e30f, sm=0.f;
    for(int ks=0;ks<SK;ks++){ float v=qk[t][ks]; mx=fmaxf(mx,v); sm+=v; }
    Mv[t]=mx-sm/(float)SK;
  }
  __syncthreads();
  if(t<64){
    bool sel=false;
    if(t<U_){
      float m=Mv[t]; int rank=0;
      for(int u2=0;u2<U_;u2++){
        float o=Mv[u2];
        if(o>m || (o==m && u2<t)) rank++;
      }
      sel=(rank<NTOP);
    }
    unsigned long long bal=__ballot(sel);
    if(t==0) selmask[bh]=(unsigned)(bal&0x3FFFFFull);
  }
}

// ---------------- K4: enc fp32 -> enc_bf16 [l][c]  AND  encT_bf16 [c][l] ----
__global__ void k_convert(const float* __restrict__ enc, u16* __restrict__ encb,
                          u16* __restrict__ encT){
  int ct=blockIdx.x, lt=blockIdx.y, b=blockIdx.z, t=threadIdx.x;
  __shared__ __align__(16) u16 tile[64][72];
  int l0=lt*64, c0=ct*64;
  for(int p=0;p<4;p++){
    int lr=p*16+(t>>4);
    int cc=(t&15)*4;
    float4 v=*(const float4*)&enc[((size_t)b*LK+l0+lr)*C_+c0+cc];
    u16 h0=f2b(v.x),h1=f2b(v.y),h2=f2b(v.z),h3=f2b(v.w);
    ushort4v o; o[0]=h0;o[1]=h1;o[2]=h2;o[3]=h3;
    *(ushort4v*)&encb[((size_t)b*LK+l0+lr)*C_+c0+cc]=o;
    tile[cc+0][lr]=h0; tile[cc+1][lr]=h1; tile[cc+2][lr]=h2; tile[cc+3][lr]=h3;
  }
  __syncthreads();
  for(int p=0;p<2;p++){
    int cr=p*32+(t>>3), loff=(t&7)*8;
    ushort8 w=*(const ushort8*)&tile[cr][loff];
    *(ushort8*)&encT[((size_t)b*C_+c0+cr)*LK+l0+loff]=w;
  }
}

// ---------------- K5: column sums of enc (from encT rows) -------------------
__global__ void k_colsum(const u16* __restrict__ encT, float* __restrict__ encsum){
  int b=blockIdx.x;
  int w=threadIdx.x>>6, lane=threadIdx.x&63;
  int c=blockIdx.y*4+w;
  const u16* row=encT+((size_t)b*C_+c)*LK;
  float s=0.f;
  for(int i=0;i<8;i++){
    ushort8 v=*(const ushort8*)&row[(i*64+lane)*8];
    for(int j=0;j<8;j++) s+=b2f(v[j]);
  }
  for(int off=32;off;off>>=1) s+=__shfl_down(s,off);
  if(lane==0) encsum[b*C_+c]=s;
}

// ---------------- K6: scores S[b][hu][l] = q_effK @ enc^T  (bf16 MFMA) ------
// One block per (nt,b) computes ALL 192 hu rows x 128 l cols: encb is read
// exactly once chip-wide (no mt re-read). acc = 12x2 frags = 96 VGPR.
__global__ __launch_bounds__(256) void k_scores(const u16* __restrict__ encb,
                                                const u16* __restrict__ qeb,
                                                u16* __restrict__ S){
  int nt=blockIdx.x, b=blockIdx.y, t=threadIdx.x;
  __shared__ __align__(16) u16 qa[HUP][40];
  __shared__ __align__(16) u16 et[128][40];
  int l0=nt*128;
  int w=t>>6, lane=t&63;
  int arow=lane&15, kgrp=(lane>>4)*4;
  f32x4 acc[12][2];
  #pragma unroll
  for(int i=0;i<12;i++){
    acc[i][0]=(f32x4){0.f,0.f,0.f,0.f};
    acc[i][1]=(f32x4){0.f,0.f,0.f,0.f};
  }
  for(int kc=0;kc<C_;kc+=32){
    __syncthreads();
    for(int i=t;i<768;i+=256){
      int r=i>>2, off=(i&3)*8;
      *(ushort8*)&qa[r][off]=*(const ushort8*)&qeb[(size_t)r*C_+kc+off];
    }
    for(int i=t;i<512;i+=256){
      int l=i>>2, off=(i&3)*8;
      *(ushort8*)&et[l][off]=*(const ushort8*)&encb[((size_t)b*LK+l0+l)*C_+kc+off];
    }
    __syncthreads();
    short8 bf0=ldfrag(&et[w*32+arow][kgrp]);
    short8 bf1=ldfrag(&et[w*32+16+arow][kgrp]);
    #pragma unroll
    for(int m=0;m<12;m++){
      short8 af=ldfrag(&qa[m*16+arow][kgrp]);
      acc[m][0]=__builtin_amdgcn_mfma_f32_16x16x32_bf16(af,bf0,acc[m][0],0,0,0);
      acc[m][1]=__builtin_amdgcn_mfma_f32_16x16x32_bf16(af,bf1,acc[m][1],0,0,0);
    }
  }
  int dcol=lane&15, drow=(lane>>4)*4;
  #pragma unroll
  for(int m=0;m<12;m++)
    #pragma unroll
    for(int ns=0;ns<2;ns++){
      size_t base=((size_t)b*HUP+m*16+drow)*LK + l0 + w*32 + ns*16 + dcol;
      #pragma unroll
      for(int r=0;r<4;r++)
        S[base+(size_t)r*LK]=f2b(acc[m][ns][r]);
    }
}

// ---------------- K7: row softmax over l (scale 1/8), in place --------------
__global__ void k_softmax(u16* __restrict__ S){
  int hu=blockIdx.x, b=blockIdx.y, t=threadIdx.x;
  u16* row=S+((size_t)b*HUP+hu)*LK;
  __shared__ float red[8];
  __shared__ float red2[8];
  float v[16];
  ushort8 r0=*(const ushort8*)&row[t*16];
  ushort8 r1=*(const ushort8*)&row[t*16+8];
  #pragma unroll
  for(int j=0;j<8;j++){ v[j]=b2f(r0[j]); v[8+j]=b2f(r1[j]); }
  float mx=-1e30f;
  #pragma unroll
  for(int j=0;j<16;j++) mx=fmaxf(mx,v[j]);
  for(int off=32;off;off>>=1) mx=fmaxf(mx,__shfl_xor(mx,off));
  int w=t>>6, lane=t&63;
  if(lane==0) red[w]=mx;
  __syncthreads();
  mx=fmaxf(fmaxf(red[0],red[1]),fmaxf(red[2],red[3]));
  const float scale=0.125f;
  float sm=0.f;
  #pragma unroll
  for(int j=0;j<16;j++){ v[j]=__expf((v[j]-mx)*scale); sm+=v[j]; }
  for(int off=32;off;off>>=1) sm+=__shfl_xor(sm,off);
  if(lane==0) red2[w]=sm;
  __syncthreads();
  sm=red2[0]+red2[1]+red2[2]+red2[3];
  float inv=1.f/sm;
  ushort8 o0,o1;
  #pragma unroll
  for(int j=0;j<8;j++){ o0[j]=f2b(v[j]*inv); o1[j]=f2b(v[8+j]*inv); }
  *(ushort8*)&row[t*16]=o0;
  *(ushort8*)&row[t*16+8]=o1;
}

// ---------------- K8: ctxA[b][hu][c] += attn @ enc  (bf16 MFMA, K-split 4) --
// Flat grid with XCD-pinning: the 4 mt-blocks sharing one encT tile get the
// same blockIdx%8 -> same XCD L2 (f = ((g>>3)*4+j)*8 + (g&7), bijective).
__global__ __launch_bounds__(256) void k_pv(const u16* __restrict__ S,
                                            const u16* __restrict__ encT,
                                            float* __restrict__ ctxA){
  int f=blockIdx.x, t=threadIdx.x;
  int xcd=f&7, s=f>>3;
  int mt=s&3, g=(s>>2)*8+xcd;
  int nt=g>>7, bz=g&127;
  int b=bz>>2, kch=bz&3;
  __shared__ __align__(16) u16 pa[48][72];
  __shared__ __align__(16) u16 et[128][72];
  int hu0=mt*48, c0=nt*128;
  int w=t>>6, lane=t&63;
  int arow=lane&15, kgrp=(lane>>4)*4;
  f32x4 acc[3][2];
  #pragma unroll
  for(int i=0;i<3;i++)
    #pragma unroll
    for(int j=0;j<2;j++) acc[i][j]=(f32x4){0.f,0.f,0.f,0.f};
  int lbase=kch*1024;
  for(int l0=lbase;l0<lbase+1024;l0+=64){
    __syncthreads();
    for(int i=t;i<384;i+=256){
      int r=i>>3, off=(i&7)*8;
      *(ushort8*)&pa[r][off]=*(const ushort8*)&S[((size_t)b*HUP+hu0+r)*LK+l0+off];
    }
    for(int i=t;i<1024;i+=256){
      int r=i>>3, off=(i&7)*8;
      *(ushort8*)&et[r][off]=*(const ushort8*)&encT[((size_t)b*C_+c0+r)*LK+l0+off];
    }
    __syncthreads();
    #pragma unroll
    for(int ks=0;ks<2;ks++){
      short8 af0=ldfrag(&pa[arow][ks*32+kgrp]);
      short8 af1=ldfrag(&pa[16+arow][ks*32+kgrp]);
      short8 af2=ldfrag(&pa[32+arow][ks*32+kgrp]);
      #pragma unroll
      for(int ns=0;ns<2;ns++){
        short8 bf=ldfrag(&et[w*32+ns*16+arow][ks*32+kgrp]);
        acc[0][ns]=__builtin_amdgcn_mfma_f32_16x16x32_bf16(af0,bf,acc[0][ns],0,0,0);
        acc[1][ns]=__builtin_amdgcn_mfma_f32_16x16x32_bf16(af1,bf,acc[1][ns],0,0,0);
        acc[2][ns]=__builtin_amdgcn_mfma_f32_16x16x32_bf16(af2,bf,acc[2][ns],0,0,0);
      }
    }
  }
  int dcol=lane&15, drow=(lane>>4)*4;
  #pragma unroll
  for(int m=0;m<3;m++)
    #pragma unroll
    for(int ns=0;ns<2;ns++)
      #pragma unroll
      for(int r=0;r<4;r++){
        int hu=hu0+m*16+drow+r, c=c0+w*32+ns*16+dcol;
        atomicAdd(&ctxA[((size_t)b*HUP+hu)*C_+c],acc[m][ns][r]);
      }
}

// ---------------- K9: ctx[b][u][hd] = (sel? ctxA : enc_mean) @ Wv + bv ------
__global__ void k_ctxproj(const float* __restrict__ ctxA, const float* __restrict__ encsum,
                          const unsigned* __restrict__ selmask, const float* __restrict__ Wv,
                          const float* __restrict__ bv, float* __restrict__ ctx){
  int u=blockIdx.x, b=blockIdx.y, t=threadIdx.x;
  __shared__ float R[H_][C_];
  for(int h=0;h<H_;h++){
    bool sel=(selmask[b*H_+h]>>u)&1u;
    const float* src=sel? &ctxA[((size_t)b*HUP+h*U_+u)*C_] : &encsum[b*C_];
    float sc=sel? 1.f : (1.f/(float)LK);
    for(int c=t;c<C_;c+=256) R[h][c]=src[c]*sc;
  }
  __syncthreads();
  for(int hd=t;hd<C_;hd+=256){
    int h=hd>>6;
    float a=0.f;
    for(int c=0;c<C_;c++) a+=R[h][c]*Wv[(size_t)c*C_+hd];
    ctx[((size_t)(b*U_+u))*C_+hd]=a+bv[hd];
  }
}

// ---------------- K10: attn_out = ctx@Wo+bo ; x = LN(2*attn_out); + xb bf16 -
__global__ void k_wo_ln1(const float* __restrict__ ctx, const float* __restrict__ Wo,
                         const float* __restrict__ bo, const float* __restrict__ g1,
                         const float* __restrict__ be1, float* __restrict__ x,
                         u16* __restrict__ xb){
  int u=blockIdx.x, b=blockIdx.y, t=threadIdx.x;
  __shared__ float row[C_];
  __shared__ float red[8];
  size_t r0=(size_t)(b*U_+u)*C_;
  for(int c=t;c<C_;c+=256) row[c]=ctx[r0+c];
  __syncthreads();
  float a0=0.f,a1=0.f;
  for(int c=0;c<C_;c++){
    float rv=row[c];
    a0+=rv*Wo[(size_t)c*C_+t];
    a1+=rv*Wo[(size_t)c*C_+t+256];
  }
  a0=2.f*(a0+bo[t]); a1=2.f*(a1+bo[t+256]);
  float mu=blocksum(a0+a1,red)*(1.f/(float)C_);
  float d0=a0-mu, d1=a1-mu;
  float var=blocksum(d0*d0+d1*d1,red)*(1.f/(float)C_);
  float rs=rsqrtf(var+EPSF);
  float x0=d0*rs*g1[t]+be1[t];
  float x1=d1*rs*g1[t+256]+be1[t+256];
  x[r0+t]=x0;
  x[r0+t+256]=x1;
  xb[r0+t]=f2b(x0);
  xb[r0+t+256]=f2b(x1);
}

// ---------------- K10b: W1,W2 fp32 -> bf16 (one shot) -----------------------
__global__ void k_convw(const float* __restrict__ W1, const float* __restrict__ W2,
                        u16* __restrict__ W1b, u16* __restrict__ W2b){
  size_t i=((size_t)blockIdx.x*256+threadIdx.x)*8;
  const float* src; u16* dst;
  const size_t NW=(size_t)DFF*C_;
  if(i<NW){ src=W1; dst=W1b; } else { src=W2; dst=W2b; i-=NW; }
  float4 a=*(const float4*)&src[i];
  float4 b=*(const float4*)&src[i+4];
  ushort8 o;
  o[0]=f2b(a.x);o[1]=f2b(a.y);o[2]=f2b(a.z);o[3]=f2b(a.w);
  o[4]=f2b(b.x);o[5]=f2b(b.y);o[6]=f2b(b.z);o[7]=f2b(b.w);
  *(ushort8*)&dst[i]=o;
}

// ---------------- K11: ff1b = relu(xb @ W1b^T + b1)  bf16 MFMA --------------
// M=704 (22x32), N=2048 (8x256), K=512
__global__ __launch_bounds__(256) void k_ff1m(const u16* __restrict__ xb,
                                              const u16* __restrict__ W1b,
                                              const float* __restrict__ b1,
                                              u16* __restrict__ ff1b){
  int mt=blockIdx.x, ntb=blockIdx.y, t=threadIdx.x;
  __shared__ __align__(16) u16 a_lds[32][520];
  __shared__ __align__(16) u16 et[256][40];
  int m0=mt*32, n0=ntb*256;
  for(int i=t;i<32*64;i+=256){
    int r=i>>6, cc=(i&63)*8;
    *(ushort8*)&a_lds[r][cc]=*(const ushort8*)&xb[(size_t)(m0+r)*C_+cc];
  }
  int w=t>>6, lane=t&63;
  int arow=lane&15, kgrp=(lane>>4)*4;
  f32x4 acc[2][4];
  #pragma unroll
  for(int i=0;i<2;i++)
    #pragma unroll
    for(int j=0;j<4;j++) acc[i][j]=(f32x4){0.f,0.f,0.f,0.f};
  for(int kc=0;kc<C_;kc+=32){
    __syncthreads();
    for(int i=t;i<1024;i+=256){
      int n=i>>2, off=(i&3)*8;
      *(ushort8*)&et[n][off]=*(const ushort8*)&W1b[(size_t)(n0+n)*C_+kc+off];
    }
    __syncthreads();
    short8 af0=ldfrag(&a_lds[arow][kc+kgrp]);
    short8 af1=ldfrag(&a_lds[16+arow][kc+kgrp]);
    #pragma unroll
    for(int ns=0;ns<4;ns++){
      short8 bf=ldfrag(&et[w*64+ns*16+arow][kgrp]);
      acc[0][ns]=__builtin_amdgcn_mfma_f32_16x16x32_bf16(af0,bf,acc[0][ns],0,0,0);
      acc[1][ns]=__builtin_amdgcn_mfma_f32_16x16x32_bf16(af1,bf,acc[1][ns],0,0,0);
    }
  }
  int dcol=lane&15, drow=(lane>>4)*4;
  #pragma unroll
  for(int ms=0;ms<2;ms++)
    #pragma unroll
    for(int ns=0;ns<4;ns++){
      int n=n0+w*64+ns*16+dcol;
      float bb=b1[n];
      #pragma unroll
      for(int r=0;r<4;r++){
        int m=m0+ms*16+drow+r;
        float v=acc[ms][ns][r]+bb;
        ff1b[(size_t)m*DFF+n]=f2b(v>0.f?v:0.f);
      }
    }
}

// ---------------- K12: ff2 += ff1b @ W2b^T  bf16 MFMA, K-split 4 ------------
// M=704 (22x32), N=512 (2x256), K=2048 (4 chunks of 512)
__global__ __launch_bounds__(256) void k_ff2m(const u16* __restrict__ ff1b,
                                              const u16* __restrict__ W2b,
                                              float* __restrict__ out){
  int mt=blockIdx.x, ntb=blockIdx.y, kch=blockIdx.z, t=threadIdx.x;
  __shared__ __align__(16) u16 a_lds[32][520];
  __shared__ __align__(16) u16 et[256][40];
  int m0=mt*32, n0=ntb*256, k0=kch*512;
  for(int i=t;i<32*64;i+=256){
    int r=i>>6, cc=(i&63)*8;
    *(ushort8*)&a_lds[r][cc]=*(const ushort8*)&ff1b[(size_t)(m0+r)*DFF+k0+cc];
  }
  int w=t>>6, lane=t&63;
  int arow=lane&15, kgrp=(lane>>4)*4;
  f32x4 acc[2][4];
  #pragma unroll
  for(int i=0;i<2;i++)
    #pragma unroll
    for(int j=0;j<4;j++) acc[i][j]=(f32x4){0.f,0.f,0.f,0.f};
  for(int kc=0;kc<512;kc+=32){
    __syncthreads();
    for(int i=t;i<1024;i+=256){
      int n=i>>2, off=(i&3)*8;
      *(ushort8*)&et[n][off]=*(const ushort8*)&W2b[(size_t)(n0+n)*DFF+k0+kc+off];
    }
    __syncthreads();
    short8 af0=ldfrag(&a_lds[arow][kc+kgrp]);
    short8 af1=ldfrag(&a_lds[16+arow][kc+kgrp]);
    #pragma unroll
    for(int ns=0;ns<4;ns++){
      short8 bf=ldfrag(&et[w*64+ns*16+arow][kgrp]);
      acc[0][ns]=__builtin_amdgcn_mfma_f32_16x16x32_bf16(af0,bf,acc[0][ns],0,0,0);
      acc[1][ns]=__builtin_amdgcn_mfma_f32_16x16x32_bf16(af1,bf,acc[1][ns],0,0,0);
    }
  }
  int dcol=lane&15, drow=(lane>>4)*4;
  #pragma unroll
  for(int ms=0;ms<2;ms++)
    #pragma unroll
    for(int ns=0;ns<4;ns++){
      int n=n0+w*64+ns*16+dcol;
      #pragma unroll
      for(int r=0;r<4;r++){
        int m=m0+ms*16+drow+r;
        atomicAdd(&out[(size_t)m*C_+n],acc[ms][ns][r]);
      }
    }
}

// ---------------- K13: y = LN(x + ff2 + b2); forecasts = y@Wout + bout ------
__global__ void k_ln2(const float* __restrict__ x, const float* __restrict__ ff2,
                      const float* __restrict__ b2, const float* __restrict__ g2,
                      const float* __restrict__ be2, const float* __restrict__ Wout,
                      const float* __restrict__ bout, float* __restrict__ dout){
  int u=blockIdx.x, b=blockIdx.y, t=threadIdx.x;
  __shared__ float red[8];
  size_t r0=(size_t)(b*U_+u)*C_;
  float s0=x[r0+t]+ff2[r0+t]+b2[t];
  float s1=x[r0+t+256]+ff2[r0+t+256]+b2[t+256];
  float mu=blocksum(s0+s1,red)*(1.f/(float)C_);
  float d0=s0-mu, d1=s1-mu;
  float var=blocksum(d0*d0+d1*d1,red)*(1.f/(float)C_);
  float rs=rsqrtf(var+EPSF);
  float y0=d0*rs*g2[t]+be2[t];
  float y1=d1*rs*g2[t+256]+be2[t+256];
  float* Y=dout+B_*U_;
  Y[r0+t]=y0;
  Y[r0+t+256]=y1;
  float f=blocksum(y0*Wout[t]+y1*Wout[t+256],red);
  if(t==0) dout[b*U_+u]=f+bout[0];
}

extern "C" void kernel_launch(void* const* d_in, const int* in_sizes, int n_in,
                              void* d_out, int out_size, void* d_ws, size_t ws_size,
                              hipStream_t stream){
  (void)in_sizes;(void)n_in;(void)out_size;(void)ws_size;
  const float* enc =(const float*)d_in[0];
  const float* Wq  =(const float*)d_in[1];
  const float* bq  =(const float*)d_in[2];
  const float* Wk  =(const float*)d_in[3];
  // d_in[4] = bk: provably cancels (row-constant shift, softmax/max-mean invariant)
  const float* Wv  =(const float*)d_in[5];
  const float* bv  =(const float*)d_in[6];
  const float* Wo  =(const float*)d_in[7];
  const float* bo  =(const float*)d_in[8];
  const float* W1  =(const float*)d_in[9];
  const float* b1  =(const float*)d_in[10];
  const float* W2  =(const float*)d_in[11];
  const float* b2  =(const float*)d_in[12];
  const float* g1  =(const float*)d_in[13];
  const float* be1 =(const float*)d_in[14];
  const float* g2  =(const float*)d_in[15];
  const float* be2 =(const float*)d_in[16];
  const float* Wout=(const float*)d_in[17];
  const float* bout=(const float*)d_in[18];

  char* ws=(char*)d_ws;
  float*    q      =(float*)   (ws+0);           //  45,056 B
  float*    qef    =(float*)   (ws+45056);       // 393,216 B (192 rows, pad zeroed)
  u16*      qeb    =(u16*)     (ws+438272);      // 196,608 B
  unsigned* selmask=(unsigned*)(ws+634880);      //   1,024 B
  float*    encsum =(float*)   (ws+635904);      //  65,536 B
  u16*      encb   =(u16*)     (ws+701440);      // 134,217,728 B (dead after k_scores)
  u16*      encT   =(u16*)     (ws+134919168);   // 134,217,728 B
  u16*      S      =(u16*)     (ws+269136896);   //  50,331,648 B  (high water ~319.5 MB)
  // overlays into the dead encb region:
  float*    ctxA   =(float*)   (ws+701440);      //  12,582,912 B
  float*    ctx    =(float*)   (ws+13284352);    //   1,441,792 B
  float*    x      =(float*)   (ws+14726144);    //   1,441,792 B
  u16*      ff1b   =(u16*)     (ws+16167936);    //   2,883,584 B
  float*    ff2    =(float*)   (ws+21935104);    //   1,441,792 B
  u16*      W1b    =(u16*)     (ws+23376896);    //   2,097,152 B
  u16*      W2b    =(u16*)     (ws+25474048);    //   2,097,152 B
  u16*      xb     =(u16*)     (ws+27571200);    //     720,896 B

  hipLaunchKernelGGL(k_prep_q, dim3(22),      dim3(256),0,stream, Wq,bq,q);
  hipLaunchKernelGGL(k_qeff,   dim3(192),     dim3(256),0,stream, q,Wk,qef,qeb);
  hipLaunchKernelGGL(k_sample, dim3(256),     dim3(256),0,stream, enc,qef,selmask);
  hipLaunchKernelGGL(k_convert,dim3(8,64,32), dim3(256),0,stream, enc,encb,encT);
  hipLaunchKernelGGL(k_colsum, dim3(32,128),  dim3(256),0,stream, encT,encsum);
  hipLaunchKernelGGL(k_scores, dim3(32,32),   dim3(256),0,stream, encb,qeb,S);
  hipLaunchKernelGGL(k_softmax,dim3(192,32),  dim3(256),0,stream, S);
  hipMemsetAsync(ctxA,0,12582912,stream);
  hipLaunchKernelGGL(k_pv,     dim3(2048),    dim3(256),0,stream, S,encT,ctxA);
  hipLaunchKernelGGL(k_ctxproj,dim3(22,32),   dim3(256),0,stream, ctxA,encsum,selmask,Wv,bv,ctx);
  hipLaunchKernelGGL(k_convw,  dim3(1024),    dim3(256),0,stream, W1,W2,W1b,W2b);
  hipLaunchKernelGGL(k_wo_ln1, dim3(22,32),   dim3(256),0,stream, ctx,Wo,bo,g1,be1,x,xb);
  hipLaunchKernelGGL(k_ff1m,   dim3(22,8),    dim3(256),0,stream, xb,W1b,b1,ff1b);
  hipMemsetAsync(ff2,0,1441792,stream);
  hipLaunchKernelGGL(k_ff2m,   dim3(22,2,4),  dim3(256),0,stream, ff1b,W2b,ff2);
  hipLaunchKernelGGL(k_ln2,    dim3(22,32),   dim3(256),0,stream, x,ff2,b2,g2,be2,Wout,bout,(float*)d_out);
}

// Round 7
// 895.506 us; speedup vs baseline: 1.4829x; 1.0328x over previous
//
#include <hip/hip_runtime.h>
#include <math.h>

#define B_ 32
#define LK 4096
#define C_ 512
#define H_ 8
#define DH 64
#define U_ 22
#define HU 176
#define HUP 192
#define SK 45
#define NTOP 20
#define DFF 2048
#define EPSF 1e-5f

typedef unsigned short u16;
typedef __attribute__((ext_vector_type(8))) short short8;
typedef __attribute__((ext_vector_type(4))) short short4v;
typedef __attribute__((ext_vector_type(8))) unsigned short ushort8;
typedef __attribute__((ext_vector_type(4))) unsigned short ushort4v;
typedef __attribute__((ext_vector_type(4))) float f32x4;

__device__ __forceinline__ u16 f2b(float f){
  union{float f;unsigned u;} v; v.f=f;
  unsigned r=(v.u + 0x7FFFu + ((v.u>>16)&1u))>>16;
  return (u16)r;
}
__device__ __forceinline__ float b2f(u16 h){
  union{unsigned u;float f;} v; v.u=((unsigned)h)<<16; return v.f;
}
// Build an 8-elem bf16 fragment: elems 0-3 at p[0..3], elems 4-7 at p[16..19].
// Same pattern for A and B => result invariant to HW's internal k-permutation.
__device__ __forceinline__ short8 ldfrag(const u16* p){
  short4v lo=*(const short4v*)p;
  short4v hi=*(const short4v*)(p+16);
  short8 r;
  r[0]=lo[0];r[1]=lo[1];r[2]=lo[2];r[3]=lo[3];
  r[4]=hi[0];r[5]=hi[1];r[6]=hi[2];r[7]=hi[3];
  return r;
}
__device__ __forceinline__ float blocksum(float v, float* red){
  for(int off=32;off;off>>=1) v+=__shfl_xor(v,off);
  int w=threadIdx.x>>6, lane=threadIdx.x&63;
  if(lane==0) red[w]=v;
  __syncthreads();
  float r=red[0]+red[1]+red[2]+red[3];
  __syncthreads();
  return r;
}

// ---------------- K1: positional encoding -> q = pe@Wq + bq  (22 x 512) -----
__global__ void k_prep_q(const float* __restrict__ Wq, const float* __restrict__ bq,
                         float* __restrict__ q){
  __shared__ float pe[C_];
  int u=blockIdx.x, t=threadIdx.x;
  float lg = logf(10000.0f)/(float)C_;
  for(int c=t;c<C_;c+=256){
    int i=c>>1;
    float arg=(float)u*expf(-(float)(2*i)*lg);
    pe[c]=(c&1)?cosf(arg):sinf(arg);
  }
  __syncthreads();
  for(int col=t;col<C_;col+=256){
    float acc=0.f;
    for(int c=0;c<C_;c++) acc+=pe[c]*Wq[c*C_+col];
    q[u*C_+col]=acc+bq[col];
  }
}

// ---------------- K2: q_effK[hu][c] = sum_d q[u][h*64+d]*Wk[c][h*64+d] ------
__global__ void k_qeff(const float* __restrict__ q, const float* __restrict__ Wk,
                       float* __restrict__ qef, u16* __restrict__ qeb){
  int hu=blockIdx.x, t=threadIdx.x;
  int h=hu/U_, u=hu-h*U_;
  __shared__ float qr[DH];
  bool valid=(hu<HU);
  if(t<DH) qr[t]=valid? q[u*C_+h*DH+t] : 0.f;
  __syncthreads();
  for(int c=t;c<C_;c+=256){
    float acc=0.f;
    if(valid){
      const float* wrow=Wk+(size_t)c*C_+h*DH;
      for(int d=0;d<DH;d++) acc+=qr[d]*wrow[d];
    }
    qef[hu*C_+c]=acc;
    qeb[hu*C_+c]=f2b(acc);
  }
}

// ---------------- K3: sampled scores -> M -> top-20 mask (fp32 exact path) --
__global__ void k_sample(const float* __restrict__ enc, const float* __restrict__ qef,
                         unsigned* __restrict__ selmask){
  int bh=blockIdx.x, t=threadIdx.x;
  int b=bh>>3, h=bh&7;
  __shared__ float es[SK][132];
  __shared__ float qe[U_][132];
  __shared__ float qk[U_][SK+3];
  __shared__ float Mv[U_];
  float acc[4]={0.f,0.f,0.f,0.f};
  for(int c0=0;c0<C_;c0+=128){
    __syncthreads();
    for(int i=t;i<SK*128;i+=256){
      int ks=i>>7, c=i&127;
      int row=(ks*LK)/SK;
      es[ks][c]=enc[((size_t)b*LK+row)*C_+c0+c];
    }
    for(int i=t;i<U_*128;i+=256){
      int u=i>>7, c=i&127;
      qe[u][c]=qef[(h*U_+u)*C_+c0+c];
    }
    __syncthreads();
    for(int dd=0;dd<4;dd++){
      int d=t+dd*256;
      if(d<U_*SK){
        int u=d/SK, ks=d-u*SK;
        float s=0.f;
        for(int c=0;c<128;c++) s+=qe[u][c]*es[ks][c];
        acc[dd]+=s;
      }
    }
  }
  for(int dd=0;dd<4;dd++){
    int d=t+dd*256;
    if(d<U_*SK){ int u=d/SK, ks=d-u*SK; qk[u][ks]=acc[dd]; }
  }
  __syncthreads();
  if(t<U_){
    float mx=-1e30f, sm=0.f;
    for(int ks=0;ks<SK;ks++){ float v=qk[t][ks]; mx=fmaxf(mx,v); sm+=v; }
    Mv[t]=mx-sm/(float)SK;
  }
  __syncthreads();
  if(t<64){
    bool sel=false;
    if(t<U_){
      float m=Mv[t]; int rank=0;
      for(int u2=0;u2<U_;u2++){
        float o=Mv[u2];
        if(o>m || (o==m && u2<t)) rank++;
      }
      sel=(rank<NTOP);
    }
    unsigned long long bal=__ballot(sel);
    if(t==0) selmask[bh]=(unsigned)(bal&0x3FFFFFull);
  }
}

// ---------------- K4: enc fp32 -> encb [l][c] + encT [c][l] + colsum --------
// Column sums folded in via the transposed LDS tile (kills the k_colsum pass).
__global__ void k_convert(const float* __restrict__ enc, u16* __restrict__ encb,
                          u16* __restrict__ encT, float* __restrict__ encsum){
  int ct=blockIdx.x, lt=blockIdx.y, b=blockIdx.z, t=threadIdx.x;
  __shared__ __align__(16) u16 tile[64][72];
  int l0=lt*64, c0=ct*64;
  for(int p=0;p<4;p++){
    int lr=p*16+(t>>4);
    int cc=(t&15)*4;
    float4 v=*(const float4*)&enc[((size_t)b*LK+l0+lr)*C_+c0+cc];
    u16 h0=f2b(v.x),h1=f2b(v.y),h2=f2b(v.z),h3=f2b(v.w);
    ushort4v o; o[0]=h0;o[1]=h1;o[2]=h2;o[3]=h3;
    *(ushort4v*)&encb[((size_t)b*LK+l0+lr)*C_+c0+cc]=o;
    tile[cc+0][lr]=h0; tile[cc+1][lr]=h1; tile[cc+2][lr]=h2; tile[cc+3][lr]=h3;
  }
  __syncthreads();
  for(int p=0;p<2;p++){
    int cr=p*32+(t>>3), loff=(t&7)*8;
    ushort8 w=*(const ushort8*)&tile[cr][loff];
    *(ushort8*)&encT[((size_t)b*C_+c0+cr)*LK+l0+loff]=w;
  }
  // colsum: 4 threads per c-row, 16 l each, shfl-reduce, one atomic per c.
  int cr=t>>2, qq=t&3;
  float s=0.f;
  #pragma unroll
  for(int j=0;j<16;j++) s+=b2f(tile[cr][qq*16+j]);
  s+=__shfl_xor(s,1);
  s+=__shfl_xor(s,2);
  if(qq==0) atomicAdd(&encsum[b*C_+c0+cr],s);
}

// ---------------- K6: scores S[b][hu][l] = q_effK @ enc^T  (bf16 MFMA) ------
// One block per (nt,b) computes ALL 192 hu rows x 128 l cols: encb is read
// exactly once chip-wide (no mt re-read). acc = 12x2 frags = 96 VGPR.
__global__ __launch_bounds__(256) void k_scores(const u16* __restrict__ encb,
                                                const u16* __restrict__ qeb,
                                                u16* __restrict__ S){
  int nt=blockIdx.x, b=blockIdx.y, t=threadIdx.x;
  __shared__ __align__(16) u16 qa[HUP][40];
  __shared__ __align__(16) u16 et[128][40];
  int l0=nt*128;
  int w=t>>6, lane=t&63;
  int arow=lane&15, kgrp=(lane>>4)*4;
  f32x4 acc[12][2];
  #pragma unroll
  for(int i=0;i<12;i++){
    acc[i][0]=(f32x4){0.f,0.f,0.f,0.f};
    acc[i][1]=(f32x4){0.f,0.f,0.f,0.f};
  }
  for(int kc=0;kc<C_;kc+=32){
    __syncthreads();
    for(int i=t;i<768;i+=256){
      int r=i>>2, off=(i&3)*8;
      *(ushort8*)&qa[r][off]=*(const ushort8*)&qeb[(size_t)r*C_+kc+off];
    }
    for(int i=t;i<512;i+=256){
      int l=i>>2, off=(i&3)*8;
      *(ushort8*)&et[l][off]=*(const ushort8*)&encb[((size_t)b*LK+l0+l)*C_+kc+off];
    }
    __syncthreads();
    short8 bf0=ldfrag(&et[w*32+arow][kgrp]);
    short8 bf1=ldfrag(&et[w*32+16+arow][kgrp]);
    #pragma unroll
    for(int m=0;m<12;m++){
      short8 af=ldfrag(&qa[m*16+arow][kgrp]);
      acc[m][0]=__builtin_amdgcn_mfma_f32_16x16x32_bf16(af,bf0,acc[m][0],0,0,0);
      acc[m][1]=__builtin_amdgcn_mfma_f32_16x16x32_bf16(af,bf1,acc[m][1],0,0,0);
    }
  }
  int dcol=lane&15, drow=(lane>>4)*4;
  #pragma unroll
  for(int m=0;m<12;m++)
    #pragma unroll
    for(int ns=0;ns<2;ns++){
      size_t base=((size_t)b*HUP+m*16+drow)*LK + l0 + w*32 + ns*16 + dcol;
      #pragma unroll
      for(int r=0;r<4;r++)
        S[base+(size_t)r*LK]=f2b(acc[m][ns][r]);
    }
}

// ---------------- K7: row softmax over l (scale 1/8), in place --------------
__global__ void k_softmax(u16* __restrict__ S){
  int hu=blockIdx.x, b=blockIdx.y, t=threadIdx.x;
  u16* row=S+((size_t)b*HUP+hu)*LK;
  __shared__ float red[8];
  __shared__ float red2[8];
  float v[16];
  ushort8 r0=*(const ushort8*)&row[t*16];
  ushort8 r1=*(const ushort8*)&row[t*16+8];
  #pragma unroll
  for(int j=0;j<8;j++){ v[j]=b2f(r0[j]); v[8+j]=b2f(r1[j]); }
  float mx=-1e30f;
  #pragma unroll
  for(int j=0;j<16;j++) mx=fmaxf(mx,v[j]);
  for(int off=32;off;off>>=1) mx=fmaxf(mx,__shfl_xor(mx,off));
  int w=t>>6, lane=t&63;
  if(lane==0) red[w]=mx;
  __syncthreads();
  mx=fmaxf(fmaxf(red[0],red[1]),fmaxf(red[2],red[3]));
  const float scale=0.125f;
  float sm=0.f;
  #pragma unroll
  for(int j=0;j<16;j++){ v[j]=__expf((v[j]-mx)*scale); sm+=v[j]; }
  for(int off=32;off;off>>=1) sm+=__shfl_xor(sm,off);
  if(lane==0) red2[w]=sm;
  __syncthreads();
  sm=red2[0]+red2[1]+red2[2]+red2[3];
  float inv=1.f/sm;
  ushort8 o0,o1;
  #pragma unroll
  for(int j=0;j<8;j++){ o0[j]=f2b(v[j]*inv); o1[j]=f2b(v[8+j]*inv); }
  *(ushort8*)&row[t*16]=o0;
  *(ushort8*)&row[t*16+8]=o1;
}

// ---------------- K8: ctxA[b][hu][c] += attn @ enc  (bf16 MFMA) -------------
// One block per (nt,b,kch): ALL 192 hu x 128 c over a 512-l K-slice.
// encT read exactly once chip-wide; 8 waves; acc = 12x1 frags.
__global__ __launch_bounds__(512) void k_pv(const u16* __restrict__ S,
                                            const u16* __restrict__ encT,
                                            float* __restrict__ ctxA){
  int nt=blockIdx.x, b=blockIdx.y, kch=blockIdx.z, t=threadIdx.x;
  __shared__ __align__(16) u16 pa[HUP][72];
  __shared__ __align__(16) u16 et[128][72];
  int c0=nt*128;
  int wv=t>>6, lane=t&63;
  int arow=lane&15, kgrp=(lane>>4)*4;
  f32x4 acc[12];
  #pragma unroll
  for(int i=0;i<12;i++) acc[i]=(f32x4){0.f,0.f,0.f,0.f};
  int lbase=kch*512;
  for(int l0=lbase;l0<lbase+512;l0+=64){
    __syncthreads();
    for(int i=t;i<1536;i+=512){
      int r=i>>3, off=(i&7)*8;
      *(ushort8*)&pa[r][off]=*(const ushort8*)&S[((size_t)b*HUP+r)*LK+l0+off];
    }
    for(int i=t;i<1024;i+=512){
      int r=i>>3, off=(i&7)*8;
      *(ushort8*)&et[r][off]=*(const ushort8*)&encT[((size_t)b*C_+c0+r)*LK+l0+off];
    }
    __syncthreads();
    #pragma unroll
    for(int ks=0;ks<2;ks++){
      short8 bf=ldfrag(&et[wv*16+arow][ks*32+kgrp]);
      #pragma unroll
      for(int m=0;m<12;m++){
        short8 af=ldfrag(&pa[m*16+arow][ks*32+kgrp]);
        acc[m]=__builtin_amdgcn_mfma_f32_16x16x32_bf16(af,bf,acc[m],0,0,0);
      }
    }
  }
  int dcol=lane&15, drow=(lane>>4)*4;
  int c=c0+wv*16+dcol;
  #pragma unroll
  for(int m=0;m<12;m++)
    #pragma unroll
    for(int r=0;r<4;r++){
      int hu=m*16+drow+r;
      atomicAdd(&ctxA[((size_t)b*HUP+hu)*C_+c],acc[m][r]);
    }
}

// ---------------- K9: ctx[b][u][hd] = (sel? ctxA : enc_mean) @ Wv + bv ------
__global__ void k_ctxproj(const float* __restrict__ ctxA, const float* __restrict__ encsum,
                          const unsigned* __restrict__ selmask, const float* __restrict__ Wv,
                          const float* __restrict__ bv, float* __restrict__ ctx){
  int u=blockIdx.x, b=blockIdx.y, t=threadIdx.x;
  __shared__ float R[H_][C_];
  for(int h=0;h<H_;h++){
    bool sel=(selmask[b*H_+h]>>u)&1u;
    const float* src=sel? &ctxA[((size_t)b*HUP+h*U_+u)*C_] : &encsum[b*C_];
    float sc=sel? 1.f : (1.f/(float)LK);
    for(int c=t;c<C_;c+=256) R[h][c]=src[c]*sc;
  }
  __syncthreads();
  for(int hd=t;hd<C_;hd+=256){
    int h=hd>>6;
    float a=0.f;
    for(int c=0;c<C_;c++) a+=R[h][c]*Wv[(size_t)c*C_+hd];
    ctx[((size_t)(b*U_+u))*C_+hd]=a+bv[hd];
  }
}

// ---------------- K10: attn_out = ctx@Wo+bo ; x = LN(2*attn_out); + xb bf16 -
__global__ void k_wo_ln1(const float* __restrict__ ctx, const float* __restrict__ Wo,
                         const float* __restrict__ bo, const float* __restrict__ g1,
                         const float* __restrict__ be1, float* __restrict__ x,
                         u16* __restrict__ xb){
  int u=blockIdx.x, b=blockIdx.y, t=threadIdx.x;
  __shared__ float row[C_];
  __shared__ float red[8];
  size_t r0=(size_t)(b*U_+u)*C_;
  for(int c=t;c<C_;c+=256) row[c]=ctx[r0+c];
  __syncthreads();
  float a0=0.f,a1=0.f;
  for(int c=0;c<C_;c++){
    float rv=row[c];
    a0+=rv*Wo[(size_t)c*C_+t];
    a1+=rv*Wo[(size_t)c*C_+t+256];
  }
  a0=2.f*(a0+bo[t]); a1=2.f*(a1+bo[t+256]);
  float mu=blocksum(a0+a1,red)*(1.f/(float)C_);
  float d0=a0-mu, d1=a1-mu;
  float var=blocksum(d0*d0+d1*d1,red)*(1.f/(float)C_);
  float rs=rsqrtf(var+EPSF);
  float x0=d0*rs*g1[t]+be1[t];
  float x1=d1*rs*g1[t+256]+be1[t+256];
  x[r0+t]=x0;
  x[r0+t+256]=x1;
  xb[r0+t]=f2b(x0);
  xb[r0+t+256]=f2b(x1);
}

// ---------------- K10b: W1,W2 fp32 -> bf16 (one shot) -----------------------
__global__ void k_convw(const float* __restrict__ W1, const float* __restrict__ W2,
                        u16* __restrict__ W1b, u16* __restrict__ W2b){
  size_t i=((size_t)blockIdx.x*256+threadIdx.x)*8;
  const float* src; u16* dst;
  const size_t NW=(size_t)DFF*C_;
  if(i<NW){ src=W1; dst=W1b; } else { src=W2; dst=W2b; i-=NW; }
  float4 a=*(const float4*)&src[i];
  float4 b=*(const float4*)&src[i+4];
  ushort8 o;
  o[0]=f2b(a.x);o[1]=f2b(a.y);o[2]=f2b(a.z);o[3]=f2b(a.w);
  o[4]=f2b(b.x);o[5]=f2b(b.y);o[6]=f2b(b.z);o[7]=f2b(b.w);
  *(ushort8*)&dst[i]=o;
}

// ---------------- K11: ff1b = relu(xb @ W1b^T + b1)  bf16 MFMA --------------
// M=704 (22x32), N=2048 (8x256), K=512
__global__ __launch_bounds__(256) void k_ff1m(const u16* __restrict__ xb,
                                              const u16* __restrict__ W1b,
                                              const float* __restrict__ b1,
                                              u16* __restrict__ ff1b){
  int mt=blockIdx.x, ntb=blockIdx.y, t=threadIdx.x;
  __shared__ __align__(16) u16 a_lds[32][520];
  __shared__ __align__(16) u16 et[256][40];
  int m0=mt*32, n0=ntb*256;
  for(int i=t;i<32*64;i+=256){
    int r=i>>6, cc=(i&63)*8;
    *(ushort8*)&a_lds[r][cc]=*(const ushort8*)&xb[(size_t)(m0+r)*C_+cc];
  }
  int w=t>>6, lane=t&63;
  int arow=lane&15, kgrp=(lane>>4)*4;
  f32x4 acc[2][4];
  #pragma unroll
  for(int i=0;i<2;i++)
    #pragma unroll
    for(int j=0;j<4;j++) acc[i][j]=(f32x4){0.f,0.f,0.f,0.f};
  for(int kc=0;kc<C_;kc+=32){
    __syncthreads();
    for(int i=t;i<1024;i+=256){
      int n=i>>2, off=(i&3)*8;
      *(ushort8*)&et[n][off]=*(const ushort8*)&W1b[(size_t)(n0+n)*C_+kc+off];
    }
    __syncthreads();
    short8 af0=ldfrag(&a_lds[arow][kc+kgrp]);
    short8 af1=ldfrag(&a_lds[16+arow][kc+kgrp]);
    #pragma unroll
    for(int ns=0;ns<4;ns++){
      short8 bf=ldfrag(&et[w*64+ns*16+arow][kgrp]);
      acc[0][ns]=__builtin_amdgcn_mfma_f32_16x16x32_bf16(af0,bf,acc[0][ns],0,0,0);
      acc[1][ns]=__builtin_amdgcn_mfma_f32_16x16x32_bf16(af1,bf,acc[1][ns],0,0,0);
    }
  }
  int dcol=lane&15, drow=(lane>>4)*4;
  #pragma unroll
  for(int ms=0;ms<2;ms++)
    #pragma unroll
    for(int ns=0;ns<4;ns++){
      int n=n0+w*64+ns*16+dcol;
      float bb=b1[n];
      #pragma unroll
      for(int r=0;r<4;r++){
        int m=m0+ms*16+drow+r;
        float v=acc[ms][ns][r]+bb;
        ff1b[(size_t)m*DFF+n]=f2b(v>0.f?v:0.f);
      }
    }
}

// ---------------- K12: ff2 += ff1b @ W2b^T  bf16 MFMA, K-split 4 ------------
// M=704 (22x32), N=512 (2x256), K=2048 (4 chunks of 512)
__global__ __launch_bounds__(256) void k_ff2m(const u16* __restrict__ ff1b,
                                              const u16* __restrict__ W2b,
                                              float* __restrict__ out){
  int mt=blockIdx.x, ntb=blockIdx.y, kch=blockIdx.z, t=threadIdx.x;
  __shared__ __align__(16) u16 a_lds[32][520];
  __shared__ __align__(16) u16 et[256][40];
  int m0=mt*32, n0=ntb*256, k0=kch*512;
  for(int i=t;i<32*64;i+=256){
    int r=i>>6, cc=(i&63)*8;
    *(ushort8*)&a_lds[r][cc]=*(const ushort8*)&ff1b[(size_t)(m0+r)*DFF+k0+cc];
  }
  int w=t>>6, lane=t&63;
  int arow=lane&15, kgrp=(lane>>4)*4;
  f32x4 acc[2][4];
  #pragma unroll
  for(int i=0;i<2;i++)
    #pragma unroll
    for(int j=0;j<4;j++) acc[i][j]=(f32x4){0.f,0.f,0.f,0.f};
  for(int kc=0;kc<512;kc+=32){
    __syncthreads();
    for(int i=t;i<1024;i+=256){
      int n=i>>2, off=(i&3)*8;
      *(ushort8*)&et[n][off]=*(const ushort8*)&W2b[(size_t)(n0+n)*DFF+k0+kc+off];
    }
    __syncthreads();
    short8 af0=ldfrag(&a_lds[arow][kc+kgrp]);
    short8 af1=ldfrag(&a_lds[16+arow][kc+kgrp]);
    #pragma unroll
    for(int ns=0;ns<4;ns++){
      short8 bf=ldfrag(&et[w*64+ns*16+arow][kgrp]);
      acc[0][ns]=__builtin_amdgcn_mfma_f32_16x16x32_bf16(af0,bf,acc[0][ns],0,0,0);
      acc[1][ns]=__builtin_amdgcn_mfma_f32_16x16x32_bf16(af1,bf,acc[1][ns],0,0,0);
    }
  }
  int dcol=lane&15, drow=(lane>>4)*4;
  #pragma unroll
  for(int ms=0;ms<2;ms++)
    #pragma unroll
    for(int ns=0;ns<4;ns++){
      int n=n0+w*64+ns*16+dcol;
      #pragma unroll
      for(int r=0;r<4;r++){
        int m=m0+ms*16+drow+r;
        atomicAdd(&out[(size_t)m*C_+n],acc[ms][ns][r]);
      }
    }
}

// ---------------- K13: y = LN(x + ff2 + b2); forecasts = y@Wout + bout ------
__global__ void k_ln2(const float* __restrict__ x, const float* __restrict__ ff2,
                      const float* __restrict__ b2, const float* __restrict__ g2,
                      const float* __restrict__ be2, const float* __restrict__ Wout,
                      const float* __restrict__ bout, float* __restrict__ dout){
  int u=blockIdx.x, b=blockIdx.y, t=threadIdx.x;
  __shared__ float red[8];
  size_t r0=(size_t)(b*U_+u)*C_;
  float s0=x[r0+t]+ff2[r0+t]+b2[t];
  float s1=x[r0+t+256]+ff2[r0+t+256]+b2[t+256];
  float mu=blocksum(s0+s1,red)*(1.f/(float)C_);
  float d0=s0-mu, d1=s1-mu;
  float var=blocksum(d0*d0+d1*d1,red)*(1.f/(float)C_);
  float rs=rsqrtf(var+EPSF);
  float y0=d0*rs*g2[t]+be2[t];
  float y1=d1*rs*g2[t+256]+be2[t+256];
  float* Y=dout+B_*U_;
  Y[r0+t]=y0;
  Y[r0+t+256]=y1;
  float f=blocksum(y0*Wout[t]+y1*Wout[t+256],red);
  if(t==0) dout[b*U_+u]=f+bout[0];
}

extern "C" void kernel_launch(void* const* d_in, const int* in_sizes, int n_in,
                              void* d_out, int out_size, void* d_ws, size_t ws_size,
                              hipStream_t stream){
  (void)in_sizes;(void)n_in;(void)out_size;(void)ws_size;
  const float* enc =(const float*)d_in[0];
  const float* Wq  =(const float*)d_in[1];
  const float* bq  =(const float*)d_in[2];
  const float* Wk  =(const float*)d_in[3];
  // d_in[4] = bk: provably cancels (row-constant shift, softmax/max-mean invariant)
  const float* Wv  =(const float*)d_in[5];
  const float* bv  =(const float*)d_in[6];
  const float* Wo  =(const float*)d_in[7];
  const float* bo  =(const float*)d_in[8];
  const float* W1  =(const float*)d_in[9];
  const float* b1  =(const float*)d_in[10];
  const float* W2  =(const float*)d_in[11];
  const float* b2  =(const float*)d_in[12];
  const float* g1  =(const float*)d_in[13];
  const float* be1 =(const float*)d_in[14];
  const float* g2  =(const float*)d_in[15];
  const float* be2 =(const float*)d_in[16];
  const float* Wout=(const float*)d_in[17];
  const float* bout=(const float*)d_in[18];

  char* ws=(char*)d_ws;
  float*    q      =(float*)   (ws+0);           //  45,056 B
  float*    qef    =(float*)   (ws+45056);       // 393,216 B (192 rows, pad zeroed)
  u16*      qeb    =(u16*)     (ws+438272);      // 196,608 B
  unsigned* selmask=(unsigned*)(ws+634880);      //   1,024 B
  float*    encsum =(float*)   (ws+635904);      //  65,536 B
  u16*      encb   =(u16*)     (ws+701440);      // 134,217,728 B (dead after k_scores)
  u16*      encT   =(u16*)     (ws+134919168);   // 134,217,728 B
  u16*      S      =(u16*)     (ws+269136896);   //  50,331,648 B  (high water ~319.5 MB)
  // overlays into the dead encb region:
  float*    ctxA   =(float*)   (ws+701440);      //  12,582,912 B
  float*    ctx    =(float*)   (ws+13284352);    //   1,441,792 B
  float*    x      =(float*)   (ws+14726144);    //   1,441,792 B
  u16*      ff1b   =(u16*)     (ws+16167936);    //   2,883,584 B
  float*    ff2    =(float*)   (ws+21935104);    //   1,441,792 B
  u16*      W1b    =(u16*)     (ws+23376896);    //   2,097,152 B
  u16*      W2b    =(u16*)     (ws+25474048);    //   2,097,152 B
  u16*      xb     =(u16*)     (ws+27571200);    //     720,896 B

  hipLaunchKernelGGL(k_prep_q, dim3(22),      dim3(256),0,stream, Wq,bq,q);
  hipLaunchKernelGGL(k_qeff,   dim3(192),     dim3(256),0,stream, q,Wk,qef,qeb);
  hipLaunchKernelGGL(k_sample, dim3(256),     dim3(256),0,stream, enc,qef,selmask);
  hipMemsetAsync(encsum,0,65536,stream);
  hipLaunchKernelGGL(k_convert,dim3(8,64,32), dim3(256),0,stream, enc,encb,encT,encsum);
  hipLaunchKernelGGL(k_scores, dim3(32,32),   dim3(256),0,stream, encb,qeb,S);
  hipLaunchKernelGGL(k_softmax,dim3(192,32),  dim3(256),0,stream, S);
  hipMemsetAsync(ctxA,0,12582912,stream);
  hipLaunchKernelGGL(k_pv,     dim3(4,32,8),  dim3(512),0,stream, S,encT,ctxA);
  hipLaunchKernelGGL(k_ctxproj,dim3(22,32),   dim3(256),0,stream, ctxA,encsum,selmask,Wv,bv,ctx);
  hipLaunchKernelGGL(k_convw,  dim3(1024),    dim3(256),0,stream, W1,W2,W1b,W2b);
  hipLaunchKernelGGL(k_wo_ln1, dim3(22,32),   dim3(256),0,stream, ctx,Wo,bo,g1,be1,x,xb);
  hipLaunchKernelGGL(k_ff1m,   dim3(22,8),    dim3(256),0,stream, xb,W1b,b1,ff1b);
  hipMemsetAsync(ff2,0,1441792,stream);
  hipLaunchKernelGGL(k_ff2m,   dim3(22,2,4),  dim3(256),0,stream, ff1b,W2b,ff2);
  hipLaunchKernelGGL(k_ln2,    dim3(22,32),   dim3(256),0,stream, x,ff2,b2,g2,be2,Wout,bout,(float*)d_out);
}